// Round 1
// baseline (710.583 us; speedup 1.0000x reference)
//
#include <hip/hip_runtime.h>
#include <math.h>

#define HH 24
#define LLEN 2048
#define DD 128
#define BLK 64
#define NBLK 32
#define TOPK 16
#define NCHUNK 8
#define CROWS (LLEN / NCHUNK)

__device__ __forceinline__ int swz(int r, int f4) { return f4 ^ ((r >> 2) & 7); }

// ---------------- 1a: block pooling (sums; ranking-invariant scale) ----------------
__global__ __launch_bounds__(256) void pool_kernel(
    const float* __restrict__ q, const float* __restrict__ k,
    float* __restrict__ qb, float* __restrict__ kb)
{
    const int nb = blockIdx.x, h = blockIdx.y;
    const int d = threadIdx.x & 127, half = threadIdx.x >> 7;
    const size_t rs = (size_t)HH * DD;
    const float* qp = q + ((size_t)(nb * BLK + half * 32) * HH + h) * DD + d;
    const float* kp = k + ((size_t)(nb * BLK + half * 32) * HH + h) * DD + d;
    float sq = 0.f, sk = 0.f;
    #pragma unroll 8
    for (int i = 0; i < 32; ++i) { sq += qp[i * rs]; sk += kp[i * rs]; }
    __shared__ float tq[2][DD], tk[2][DD];
    tq[half][d] = sq; tk[half][d] = sk;
    __syncthreads();
    if (half == 0) {
        qb[((size_t)h * NBLK + nb) * DD + d] = tq[0][d] + tq[1][d];
        kb[((size_t)h * NBLK + nb) * DD + d] = tk[0][d] + tk[1][d];
    }
}

// ---------------- 1b: block scores + top-16 LUT ----------------
__global__ __launch_bounds__(256) void topk_kernel(
    const float* __restrict__ qb, const float* __restrict__ kb, int* __restrict__ lut)
{
    const int h = blockIdx.x;
    __shared__ float kb_s[NBLK][DD];
    __shared__ float sc[NBLK][NBLK];
    const int tid = threadIdx.x;
    for (int f = tid; f < NBLK * DD / 4; f += 256)
        ((float4*)kb_s)[f] = ((const float4*)(kb + (size_t)h * NBLK * DD))[f];
    __syncthreads();
    for (int p = tid; p < NBLK * NBLK; p += 256) {
        const int iq = p >> 5, ik = p & 31;
        const float4* qr4 = (const float4*)(qb + ((size_t)h * NBLK + iq) * DD);
        const float4* kr4 = (const float4*)&kb_s[ik][0];
        float s = 0.f;
        for (int dq = 0; dq < DD / 4; ++dq) {
            float4 a = qr4[dq], b = kr4[dq];
            s += a.x * b.x + a.y * b.y + a.z * b.z + a.w * b.w;
        }
        sc[iq][ik] = s;
    }
    __syncthreads();
    if (tid < NBLK) {
        const int iq = tid;
        for (int t = 0; t < TOPK; ++t) {
            float bv = -1e30f; int bi = 0;
            for (int j = 0; j < NBLK; ++j) {
                float s = sc[iq][j];
                if (s > bv) { bv = s; bi = j; }
            }
            lut[((size_t)h * NBLK + iq) * TOPK + t] = bi;
            sc[iq][bi] = -1e30f;
        }
    }
}

// ---------------- 2: partial kvsum = kl^T v and ksum, per (head, L-chunk) ----------------
__global__ __launch_bounds__(256) void kv_partial(
    const float* __restrict__ k, const float* __restrict__ v,
    float* __restrict__ kvp, float* __restrict__ ksp)
{
    const int h = blockIdx.x, c = blockIdx.y;
    __shared__ float kl_s[8][DD];
    __shared__ float v_s[8][DD];
    __shared__ float redm[8], redr[8];
    const int tid = threadIdx.x;
    const int ty = tid >> 4, tx = tid & 15;
    const int d0 = ty * 8, e0 = tx * 8;
    float acc[8][8];
    #pragma unroll
    for (int i = 0; i < 8; ++i)
        #pragma unroll
        for (int j = 0; j < 8; ++j) acc[i][j] = 0.f;
    float ksa[8];
    #pragma unroll
    for (int i = 0; i < 8; ++i) ksa[i] = 0.f;
    const int l0 = c * CROWS;

    for (int rg = 0; rg < CROWS; rg += 8) {
        {
            const int r = tid >> 5, d4 = tid & 31;
            const size_t gb = ((size_t)(l0 + rg + r) * HH + h) * DD;
            ((float4*)&kl_s[r][0])[d4] = ((const float4*)(k + gb))[d4];
            ((float4*)&v_s[r][0])[d4]  = ((const float4*)(v + gb))[d4];
        }
        __syncthreads();
        if (tid < 64) {
            const int r = tid >> 3, ln = tid & 7;
            float m = -1e30f;
            for (int dd = ln; dd < DD; dd += 8) m = fmaxf(m, kl_s[r][dd]);
            m = fmaxf(m, __shfl_xor(m, 1));
            m = fmaxf(m, __shfl_xor(m, 2));
            m = fmaxf(m, __shfl_xor(m, 4));
            float s = 0.f;
            for (int dd = ln; dd < DD; dd += 8) s += __expf(kl_s[r][dd] - m);
            s += __shfl_xor(s, 1);
            s += __shfl_xor(s, 2);
            s += __shfl_xor(s, 4);
            if (ln == 0) { redm[r] = m; redr[r] = 1.0f / s; }
        }
        __syncthreads();
        {
            const int r = tid >> 5, d4 = tid & 31;
            float4 x = ((float4*)&kl_s[r][0])[d4];
            const float m = redm[r], rr = redr[r];
            x.x = __expf(x.x - m) * rr;
            x.y = __expf(x.y - m) * rr;
            x.z = __expf(x.z - m) * rr;
            x.w = __expf(x.w - m) * rr;
            ((float4*)&kl_s[r][0])[d4] = x;
        }
        __syncthreads();
        #pragma unroll
        for (int r = 0; r < 8; ++r) {
            float4 ka = ((const float4*)&kl_s[r][0])[ty * 2];
            float4 kb4 = ((const float4*)&kl_s[r][0])[ty * 2 + 1];
            float4 va = ((const float4*)&v_s[r][0])[tx * 2];
            float4 vb = ((const float4*)&v_s[r][0])[tx * 2 + 1];
            float kk[8] = {ka.x, ka.y, ka.z, ka.w, kb4.x, kb4.y, kb4.z, kb4.w};
            float vv[8] = {va.x, va.y, va.z, va.w, vb.x, vb.y, vb.z, vb.w};
            #pragma unroll
            for (int i = 0; i < 8; ++i)
                #pragma unroll
                for (int j = 0; j < 8; ++j) acc[i][j] += kk[i] * vv[j];
            if (tx == 0) {
                #pragma unroll
                for (int i = 0; i < 8; ++i) ksa[i] += kk[i];
            }
        }
        __syncthreads();
    }
    float* op = kvp + ((size_t)h * NCHUNK + c) * DD * DD;
    #pragma unroll
    for (int i = 0; i < 8; ++i) {
        float4 o0 = make_float4(acc[i][0], acc[i][1], acc[i][2], acc[i][3]);
        float4 o1 = make_float4(acc[i][4], acc[i][5], acc[i][6], acc[i][7]);
        ((float4*)(op + (size_t)(d0 + i) * DD + e0))[0] = o0;
        ((float4*)(op + (size_t)(d0 + i) * DD + e0))[1] = o1;
    }
    if (tx == 0) {
        float* kp2 = ksp + ((size_t)h * NCHUNK + c) * DD + d0;
        #pragma unroll
        for (int i = 0; i < 8; ++i) kp2[i] = ksa[i];
    }
}

// ---------------- 3: reduce partials; M = kvsum @ W^T; final ksum ----------------
__global__ __launch_bounds__(256) void reduce_M(
    const float* __restrict__ kvp, const float* __restrict__ ksp,
    const float* __restrict__ W, float* __restrict__ Mw, float* __restrict__ ksumf)
{
    const int h = blockIdx.x;
    __shared__ float kv_s[DD][DD];
    const int tid = threadIdx.x;
    for (int f = tid; f < DD * DD / 4; f += 256) {
        float4 s = make_float4(0.f, 0.f, 0.f, 0.f);
        #pragma unroll
        for (int c2 = 0; c2 < NCHUNK; ++c2) {
            float4 x = ((const float4*)(kvp + ((size_t)h * NCHUNK + c2) * DD * DD))[f];
            s.x += x.x; s.y += x.y; s.z += x.z; s.w += x.w;
        }
        ((float4*)kv_s)[f] = s;
    }
    if (tid < DD) {
        float s = 0.f;
        #pragma unroll
        for (int c2 = 0; c2 < NCHUNK; ++c2)
            s += ksp[((size_t)h * NCHUNK + c2) * DD + tid];
        ksumf[(size_t)h * DD + tid] = s;
    }
    __syncthreads();
    const int ty = tid >> 4, tx = tid & 15;
    const int dd0 = ty * 8, e20 = tx * 8;
    float acc[8][8];
    #pragma unroll
    for (int i = 0; i < 8; ++i)
        #pragma unroll
        for (int j = 0; j < 8; ++j) acc[i][j] = 0.f;
    for (int eq = 0; eq < DD / 4; ++eq) {
        float4 kvv[8], wv[8];
        #pragma unroll
        for (int i = 0; i < 8; ++i) kvv[i] = ((const float4*)&kv_s[dd0 + i][0])[eq];
        #pragma unroll
        for (int j = 0; j < 8; ++j) wv[j] = ((const float4*)(W + (size_t)(e20 + j) * DD))[eq];
        #pragma unroll
        for (int i = 0; i < 8; ++i)
            #pragma unroll
            for (int j = 0; j < 8; ++j)
                acc[i][j] += kvv[i].x * wv[j].x + kvv[i].y * wv[j].y
                           + kvv[i].z * wv[j].z + kvv[i].w * wv[j].w;
    }
    float* op = Mw + (size_t)h * DD * DD;
    #pragma unroll
    for (int i = 0; i < 8; ++i) {
        float4 o0 = make_float4(acc[i][0], acc[i][1], acc[i][2], acc[i][3]);
        float4 o1 = make_float4(acc[i][4], acc[i][5], acc[i][6], acc[i][7]);
        ((float4*)(op + (size_t)(dd0 + i) * DD + e20))[0] = o0;
        ((float4*)(op + (size_t)(dd0 + i) * DD + e20))[1] = o1;
    }
}

// ---------------- 4: block-sparse flash attention (fp32) ----------------
__global__ __launch_bounds__(256) void sparse_attn(
    const float* __restrict__ q, const float* __restrict__ k, const float* __restrict__ v,
    const int* __restrict__ lut, float* __restrict__ out)
{
    const int nq = blockIdx.x, h = blockIdx.y;
    __shared__ float Qs[BLK][DD];   // 32 KiB
    __shared__ float KVs[BLK][DD];  // 32 KiB (K, then reused for V)
    __shared__ float Ss[BLK][BLK];  // 16 KiB  -> exactly 80 KiB total: 2 blocks/CU
    const int tid = threadIdx.x;
    const int ti = tid >> 4, tj = tid & 15;
    const int i0 = ti * 4, c0 = tj * 8;
    const int r_sm = tid >> 2, sg = tid & 3;

    for (int f = tid; f < BLK * (DD / 4); f += 256) {
        const int r = f >> 5, d4 = f & 31;
        ((float4*)&Qs[r][0])[swz(r, d4)] =
            ((const float4*)(q + ((size_t)(nq * BLK + r) * HH + h) * DD))[d4];
    }
    float Oa[4][8];
    #pragma unroll
    for (int a = 0; a < 4; ++a)
        #pragma unroll
        for (int j = 0; j < 8; ++j) Oa[a][j] = 0.f;
    float m_run = -1e30f, l_run = 0.f;
    __syncthreads();

    const int* lrow = lut + ((size_t)h * NBLK + nq) * TOPK;
    for (int it = 0; it < TOPK; ++it) {
        const int kbI = lrow[it];
        for (int f = tid; f < BLK * (DD / 4); f += 256) {
            const int r = f >> 5, d4 = f & 31;
            ((float4*)&KVs[r][0])[swz(r, d4)] =
                ((const float4*)(k + ((size_t)(kbI * BLK + r) * HH + h) * DD))[d4];
        }
        __syncthreads();
        // S = scale * Q K^T, 4x4 per thread
        {
            float acc[4][4];
            #pragma unroll
            for (int a = 0; a < 4; ++a)
                #pragma unroll
                for (int b = 0; b < 4; ++b) acc[a][b] = 0.f;
            for (int dq = 0; dq < DD / 4; ++dq) {
                float4 qv[4], kv[4];
                #pragma unroll
                for (int a = 0; a < 4; ++a)
                    qv[a] = ((const float4*)&Qs[i0 + a][0])[swz(i0 + a, dq)];
                #pragma unroll
                for (int b = 0; b < 4; ++b)
                    kv[b] = ((const float4*)&KVs[tj * 4 + b][0])[swz(tj * 4 + b, dq)];
                #pragma unroll
                for (int a = 0; a < 4; ++a)
                    #pragma unroll
                    for (int b = 0; b < 4; ++b)
                        acc[a][b] += qv[a].x * kv[b].x + qv[a].y * kv[b].y
                                   + qv[a].z * kv[b].z + qv[a].w * kv[b].w;
            }
            const float scale = 0.08838834764831845f;
            #pragma unroll
            for (int a = 0; a < 4; ++a) {
                float4 sv = make_float4(acc[a][0] * scale, acc[a][1] * scale,
                                        acc[a][2] * scale, acc[a][3] * scale);
                ((float4*)&Ss[i0 + a][0])[swz(i0 + a, tj)] = sv;
            }
        }
        // online softmax: 4 lanes per row; S row produced by same 16-lane cluster (intra-wave)
        float alpha;
        {
            float4 s4[4];
            #pragma unroll
            for (int u = 0; u < 4; ++u)
                s4[u] = ((const float4*)&Ss[r_sm][0])[swz(r_sm, sg * 4 + u)];
            float mx = -1e30f;
            #pragma unroll
            for (int u = 0; u < 4; ++u)
                mx = fmaxf(mx, fmaxf(fmaxf(s4[u].x, s4[u].y), fmaxf(s4[u].z, s4[u].w)));
            mx = fmaxf(mx, __shfl_xor(mx, 1));
            mx = fmaxf(mx, __shfl_xor(mx, 2));
            const float mnew = fmaxf(m_run, mx);
            float ss = 0.f;
            #pragma unroll
            for (int u = 0; u < 4; ++u) {
                s4[u].x = __expf(s4[u].x - mnew); ss += s4[u].x;
                s4[u].y = __expf(s4[u].y - mnew); ss += s4[u].y;
                s4[u].z = __expf(s4[u].z - mnew); ss += s4[u].z;
                s4[u].w = __expf(s4[u].w - mnew); ss += s4[u].w;
                ((float4*)&Ss[r_sm][0])[swz(r_sm, sg * 4 + u)] = s4[u];
            }
            ss += __shfl_xor(ss, 1);
            ss += __shfl_xor(ss, 2);
            alpha = __expf(m_run - mnew);
            l_run = l_run * alpha + ss;
            m_run = mnew;
        }
        __syncthreads();   // all waves done reading K before V overwrites KVs
        for (int f = tid; f < BLK * (DD / 4); f += 256) {
            const int r = f >> 5, d4 = f & 31;
            ((float4*)&KVs[r][0])[swz(r, d4)] =
                ((const float4*)(v + ((size_t)(kbI * BLK + r) * HH + h) * DD))[d4];
        }
        __syncthreads();
        // O = O*alpha + P V, 4x8 per thread
        {
            #pragma unroll
            for (int a = 0; a < 4; ++a) {
                const float al = __shfl(alpha, ((i0 + a) << 2) & 63);
                #pragma unroll
                for (int j = 0; j < 8; ++j) Oa[a][j] *= al;
            }
            for (int jq = 0; jq < BLK / 4; ++jq) {
                float4 pv[4];
                #pragma unroll
                for (int a = 0; a < 4; ++a)
                    pv[a] = ((const float4*)&Ss[i0 + a][0])[swz(i0 + a, jq)];
                #pragma unroll
                for (int b = 0; b < 4; ++b) {
                    const int jj = jq * 4 + b;
                    const float4 v0 = ((const float4*)&KVs[jj][0])[swz(jj, tj * 2)];
                    const float4 v1 = ((const float4*)&KVs[jj][0])[swz(jj, tj * 2 + 1)];
                    #pragma unroll
                    for (int a = 0; a < 4; ++a) {
                        const float p = ((const float*)&pv[a])[b];
                        Oa[a][0] += p * v0.x; Oa[a][1] += p * v0.y;
                        Oa[a][2] += p * v0.z; Oa[a][3] += p * v0.w;
                        Oa[a][4] += p * v1.x; Oa[a][5] += p * v1.y;
                        Oa[a][6] += p * v1.z; Oa[a][7] += p * v1.w;
                    }
                }
            }
        }
        __syncthreads();   // done reading Ss/KVs before next iteration overwrites
    }
    #pragma unroll
    for (int a = 0; a < 4; ++a) {
        const float lr = __shfl(l_run, ((i0 + a) << 2) & 63);
        const float rl = 1.0f / lr;
        float* dst = out + ((size_t)(nq * BLK + i0 + a) * HH + h) * DD + c0;
        float4 o0 = make_float4(Oa[a][0] * rl, Oa[a][1] * rl, Oa[a][2] * rl, Oa[a][3] * rl);
        float4 o1 = make_float4(Oa[a][4] * rl, Oa[a][5] * rl, Oa[a][6] * rl, Oa[a][7] * rl);
        ((float4*)dst)[0] = o0;
        ((float4*)dst)[1] = o1;
    }
}

// ---------------- 5: linear-attn output: out += (ql @ M)/den + b ----------------
__global__ __launch_bounds__(256) void linear_out(
    const float* __restrict__ q, const float* __restrict__ Mw,
    const float* __restrict__ ksumf, const float* __restrict__ pb,
    float* __restrict__ out)
{
    const int c = blockIdx.x, h = blockIdx.y;
    __shared__ float M_s[DD][DD];
    __shared__ float ql_s[BLK][DD];
    __shared__ float dinv_s[BLK];
    __shared__ float b_s[DD];
    const int tid = threadIdx.x;
    for (int f = tid; f < DD * DD / 4; f += 256)
        ((float4*)M_s)[f] = ((const float4*)(Mw + (size_t)h * DD * DD))[f];
    if (tid < DD) b_s[tid] = pb[tid];
    {
        const int r = tid >> 2, sg = tid & 3;
        const float* qrow = q + ((size_t)(c * BLK + r) * HH + h) * DD + sg * 32;
        float vals[32];
        float mx = -1e30f;
        #pragma unroll
        for (int u = 0; u < 32; ++u) { vals[u] = qrow[u]; mx = fmaxf(mx, vals[u]); }
        mx = fmaxf(mx, __shfl_xor(mx, 1));
        mx = fmaxf(mx, __shfl_xor(mx, 2));
        float s = 0.f;
        #pragma unroll
        for (int u = 0; u < 32; ++u) { vals[u] = __expf(vals[u] - mx); s += vals[u]; }
        s += __shfl_xor(s, 1);
        s += __shfl_xor(s, 2);
        const float rinv = 1.0f / s;
        const float* ks = ksumf + (size_t)h * DD + sg * 32;
        float den = 0.f;
        #pragma unroll
        for (int u = 0; u < 32; ++u) {
            const float ql = vals[u] * rinv;
            ql_s[r][sg * 32 + u] = ql;
            den += ql * ks[u];
        }
        den += __shfl_xor(den, 1);
        den += __shfl_xor(den, 2);
        if (sg == 0) dinv_s[r] = 1.0f / (1e-5f + den);
    }
    __syncthreads();
    const int ti = tid >> 4, tj = tid & 15;
    const int i0 = ti * 4, e0 = tj * 8;
    float acc[4][8];
    #pragma unroll
    for (int a = 0; a < 4; ++a)
        #pragma unroll
        for (int j = 0; j < 8; ++j) acc[a][j] = 0.f;
    for (int dq = 0; dq < DD / 4; ++dq) {
        float4 qv[4];
        #pragma unroll
        for (int a = 0; a < 4; ++a) qv[a] = ((const float4*)&ql_s[i0 + a][0])[dq];
        #pragma unroll
        for (int dd = 0; dd < 4; ++dd) {
            const int d = dq * 4 + dd;
            const float4 m0 = ((const float4*)&M_s[d][0])[tj * 2];
            const float4 m1 = ((const float4*)&M_s[d][0])[tj * 2 + 1];
            #pragma unroll
            for (int a = 0; a < 4; ++a) {
                const float qq = ((const float*)&qv[a])[dd];
                acc[a][0] += qq * m0.x; acc[a][1] += qq * m0.y;
                acc[a][2] += qq * m0.z; acc[a][3] += qq * m0.w;
                acc[a][4] += qq * m1.x; acc[a][5] += qq * m1.y;
                acc[a][6] += qq * m1.z; acc[a][7] += qq * m1.w;
            }
        }
    }
    #pragma unroll
    for (int a = 0; a < 4; ++a) {
        const float di = dinv_s[i0 + a];
        float* dst = out + ((size_t)(c * BLK + i0 + a) * HH + h) * DD + e0;
        float4 o0 = ((float4*)dst)[0];
        float4 o1 = ((float4*)dst)[1];
        o0.x += acc[a][0] * di + b_s[e0 + 0];
        o0.y += acc[a][1] * di + b_s[e0 + 1];
        o0.z += acc[a][2] * di + b_s[e0 + 2];
        o0.w += acc[a][3] * di + b_s[e0 + 3];
        o1.x += acc[a][4] * di + b_s[e0 + 4];
        o1.y += acc[a][5] * di + b_s[e0 + 5];
        o1.z += acc[a][6] * di + b_s[e0 + 6];
        o1.w += acc[a][7] * di + b_s[e0 + 7];
        ((float4*)dst)[0] = o0;
        ((float4*)dst)[1] = o1;
    }
}

extern "C" void kernel_launch(void* const* d_in, const int* in_sizes, int n_in,
                              void* d_out, int out_size, void* d_ws, size_t ws_size,
                              hipStream_t stream)
{
    (void)in_sizes; (void)n_in; (void)out_size; (void)ws_size;
    const float* q  = (const float*)d_in[0];
    const float* k  = (const float*)d_in[1];
    const float* v  = (const float*)d_in[2];
    const float* pw = (const float*)d_in[3];
    const float* pb = (const float*)d_in[4];
    float* out = (float*)d_out;
    char* ws = (char*)d_ws;
    size_t off = 0;
    int*   lut   = (int*)(ws + off);   off += (size_t)HH * NBLK * TOPK * 4;
    float* qb    = (float*)(ws + off); off += (size_t)HH * NBLK * DD * 4;
    float* kb    = (float*)(ws + off); off += (size_t)HH * NBLK * DD * 4;
    float* kvp   = (float*)(ws + off); off += (size_t)HH * NCHUNK * DD * DD * 4;
    float* ksp   = (float*)(ws + off); off += (size_t)HH * NCHUNK * DD * 4;
    float* Mw    = (float*)(ws + off); off += (size_t)HH * DD * DD * 4;
    float* ksumf = (float*)(ws + off); off += (size_t)HH * DD * 4;

    pool_kernel<<<dim3(NBLK, HH), 256, 0, stream>>>(q, k, qb, kb);
    topk_kernel<<<HH, 256, 0, stream>>>(qb, kb, lut);
    kv_partial<<<dim3(HH, NCHUNK), 256, 0, stream>>>(k, v, kvp, ksp);
    reduce_M<<<HH, 256, 0, stream>>>(kvp, ksp, pw, Mw, ksumf);
    sparse_attn<<<dim3(NBLK, HH), 256, 0, stream>>>(q, k, v, lut, out);
    linear_out<<<dim3(NBLK, HH), 256, 0, stream>>>(q, Mw, ksumf, pb, out);
}

// Round 2
// 323.917 us; speedup vs baseline: 2.1937x; 2.1937x over previous
//
#include <hip/hip_runtime.h>
#include <math.h>

#define HH 24
#define LLEN 2048
#define DD 128
#define BLK 64
#define NBLK 32
#define TOPK 16
#define NCHUNK 8
#define CROWS (LLEN / NCHUNK)

typedef __attribute__((ext_vector_type(8))) short bf16x8;
typedef __attribute__((ext_vector_type(4))) float f32x4;

__device__ __forceinline__ unsigned short f2bf(float f) {
    unsigned u = __builtin_bit_cast(unsigned, f);
    unsigned r = (u + 0x7FFFu + ((u >> 16) & 1u)) >> 16;
    return (unsigned short)r;
}
__device__ __forceinline__ float bf2f(unsigned short b) {
    unsigned u = ((unsigned)b) << 16;
    return __builtin_bit_cast(float, u);
}

__device__ __forceinline__ int swz(int r, int f4) { return f4 ^ ((r >> 2) & 7); }

// ---------------- 1a: block pooling (sums; ranking-invariant scale) ----------------
__global__ __launch_bounds__(256) void pool_kernel(
    const float* __restrict__ q, const float* __restrict__ k,
    float* __restrict__ qb, float* __restrict__ kb)
{
    const int nb = blockIdx.x, h = blockIdx.y;
    const int d = threadIdx.x & 127, half = threadIdx.x >> 7;
    const size_t rs = (size_t)HH * DD;
    const float* qp = q + ((size_t)(nb * BLK + half * 32) * HH + h) * DD + d;
    const float* kp = k + ((size_t)(nb * BLK + half * 32) * HH + h) * DD + d;
    float sq = 0.f, sk = 0.f;
    #pragma unroll 8
    for (int i = 0; i < 32; ++i) { sq += qp[i * rs]; sk += kp[i * rs]; }
    __shared__ float tq[2][DD], tk[2][DD];
    tq[half][d] = sq; tk[half][d] = sk;
    __syncthreads();
    if (half == 0) {
        qb[((size_t)h * NBLK + nb) * DD + d] = tq[0][d] + tq[1][d];
        kb[((size_t)h * NBLK + nb) * DD + d] = tk[0][d] + tk[1][d];
    }
}

// ---------------- 1b: block scores + top-16 LUT ----------------
__global__ __launch_bounds__(256) void topk_kernel(
    const float* __restrict__ qb, const float* __restrict__ kb, int* __restrict__ lut)
{
    const int h = blockIdx.x;
    __shared__ float kb_s[NBLK][DD];
    __shared__ float sc[NBLK][NBLK];
    const int tid = threadIdx.x;
    for (int f = tid; f < NBLK * DD / 4; f += 256)
        ((float4*)kb_s)[f] = ((const float4*)(kb + (size_t)h * NBLK * DD))[f];
    __syncthreads();
    for (int p = tid; p < NBLK * NBLK; p += 256) {
        const int iq = p >> 5, ik = p & 31;
        const float4* qr4 = (const float4*)(qb + ((size_t)h * NBLK + iq) * DD);
        const float4* kr4 = (const float4*)&kb_s[ik][0];
        float s = 0.f;
        for (int dq = 0; dq < DD / 4; ++dq) {
            float4 a = qr4[dq], b = kr4[dq];
            s += a.x * b.x + a.y * b.y + a.z * b.z + a.w * b.w;
        }
        sc[iq][ik] = s;
    }
    __syncthreads();
    if (tid < NBLK) {
        const int iq = tid;
        for (int t = 0; t < TOPK; ++t) {
            float bv = -1e30f; int bi = 0;
            for (int j = 0; j < NBLK; ++j) {
                float s = sc[iq][j];
                if (s > bv) { bv = s; bi = j; }
            }
            lut[((size_t)h * NBLK + iq) * TOPK + t] = bi;
            sc[iq][bi] = -1e30f;
        }
    }
}

// ---------------- 2: partial kvsum = kl^T v and ksum, per (head, L-chunk) ----------------
__global__ __launch_bounds__(256) void kv_partial(
    const float* __restrict__ k, const float* __restrict__ v,
    float* __restrict__ kvp, float* __restrict__ ksp)
{
    const int h = blockIdx.x, c = blockIdx.y;
    __shared__ float kl_s[8][DD];
    __shared__ float v_s[8][DD];
    __shared__ float redm[8], redr[8];
    const int tid = threadIdx.x;
    const int ty = tid >> 4, tx = tid & 15;
    const int d0 = ty * 8, e0 = tx * 8;
    float acc[8][8];
    #pragma unroll
    for (int i = 0; i < 8; ++i)
        #pragma unroll
        for (int j = 0; j < 8; ++j) acc[i][j] = 0.f;
    float ksa[8];
    #pragma unroll
    for (int i = 0; i < 8; ++i) ksa[i] = 0.f;
    const int l0 = c * CROWS;

    for (int rg = 0; rg < CROWS; rg += 8) {
        {
            const int r = tid >> 5, d4 = tid & 31;
            const size_t gb = ((size_t)(l0 + rg + r) * HH + h) * DD;
            ((float4*)&kl_s[r][0])[d4] = ((const float4*)(k + gb))[d4];
            ((float4*)&v_s[r][0])[d4]  = ((const float4*)(v + gb))[d4];
        }
        __syncthreads();
        if (tid < 64) {
            const int r = tid >> 3, ln = tid & 7;
            float m = -1e30f;
            for (int dd = ln; dd < DD; dd += 8) m = fmaxf(m, kl_s[r][dd]);
            m = fmaxf(m, __shfl_xor(m, 1));
            m = fmaxf(m, __shfl_xor(m, 2));
            m = fmaxf(m, __shfl_xor(m, 4));
            float s = 0.f;
            for (int dd = ln; dd < DD; dd += 8) s += __expf(kl_s[r][dd] - m);
            s += __shfl_xor(s, 1);
            s += __shfl_xor(s, 2);
            s += __shfl_xor(s, 4);
            if (ln == 0) { redm[r] = m; redr[r] = 1.0f / s; }
        }
        __syncthreads();
        {
            const int r = tid >> 5, d4 = tid & 31;
            float4 x = ((float4*)&kl_s[r][0])[d4];
            const float m = redm[r], rr = redr[r];
            x.x = __expf(x.x - m) * rr;
            x.y = __expf(x.y - m) * rr;
            x.z = __expf(x.z - m) * rr;
            x.w = __expf(x.w - m) * rr;
            ((float4*)&kl_s[r][0])[d4] = x;
        }
        __syncthreads();
        #pragma unroll
        for (int r = 0; r < 8; ++r) {
            float4 ka = ((const float4*)&kl_s[r][0])[ty * 2];
            float4 kb4 = ((const float4*)&kl_s[r][0])[ty * 2 + 1];
            float4 va = ((const float4*)&v_s[r][0])[tx * 2];
            float4 vb = ((const float4*)&v_s[r][0])[tx * 2 + 1];
            float kk[8] = {ka.x, ka.y, ka.z, ka.w, kb4.x, kb4.y, kb4.z, kb4.w};
            float vv[8] = {va.x, va.y, va.z, va.w, vb.x, vb.y, vb.z, vb.w};
            #pragma unroll
            for (int i = 0; i < 8; ++i)
                #pragma unroll
                for (int j = 0; j < 8; ++j) acc[i][j] += kk[i] * vv[j];
            if (tx == 0) {
                #pragma unroll
                for (int i = 0; i < 8; ++i) ksa[i] += kk[i];
            }
        }
        __syncthreads();
    }
    float* op = kvp + ((size_t)h * NCHUNK + c) * DD * DD;
    #pragma unroll
    for (int i = 0; i < 8; ++i) {
        float4 o0 = make_float4(acc[i][0], acc[i][1], acc[i][2], acc[i][3]);
        float4 o1 = make_float4(acc[i][4], acc[i][5], acc[i][6], acc[i][7]);
        ((float4*)(op + (size_t)(d0 + i) * DD + e0))[0] = o0;
        ((float4*)(op + (size_t)(d0 + i) * DD + e0))[1] = o1;
    }
    if (tx == 0) {
        float* kp2 = ksp + ((size_t)h * NCHUNK + c) * DD + d0;
        #pragma unroll
        for (int i = 0; i < 8; ++i) kp2[i] = ksa[i];
    }
}

// ---------------- 3: reduce partials; M = kvsum @ W^T; final ksum ----------------
__global__ __launch_bounds__(256) void reduce_M(
    const float* __restrict__ kvp, const float* __restrict__ ksp,
    const float* __restrict__ W, float* __restrict__ Mw, float* __restrict__ ksumf)
{
    const int h = blockIdx.x;
    __shared__ float kv_s[DD][DD];
    const int tid = threadIdx.x;
    for (int f = tid; f < DD * DD / 4; f += 256) {
        float4 s = make_float4(0.f, 0.f, 0.f, 0.f);
        #pragma unroll
        for (int c2 = 0; c2 < NCHUNK; ++c2) {
            float4 x = ((const float4*)(kvp + ((size_t)h * NCHUNK + c2) * DD * DD))[f];
            s.x += x.x; s.y += x.y; s.z += x.z; s.w += x.w;
        }
        ((float4*)kv_s)[f] = s;
    }
    if (tid < DD) {
        float s = 0.f;
        #pragma unroll
        for (int c2 = 0; c2 < NCHUNK; ++c2)
            s += ksp[((size_t)h * NCHUNK + c2) * DD + tid];
        ksumf[(size_t)h * DD + tid] = s;
    }
    __syncthreads();
    const int ty = tid >> 4, tx = tid & 15;
    const int dd0 = ty * 8, e20 = tx * 8;
    float acc[8][8];
    #pragma unroll
    for (int i = 0; i < 8; ++i)
        #pragma unroll
        for (int j = 0; j < 8; ++j) acc[i][j] = 0.f;
    for (int eq = 0; eq < DD / 4; ++eq) {
        float4 kvv[8], wv[8];
        #pragma unroll
        for (int i = 0; i < 8; ++i) kvv[i] = ((const float4*)&kv_s[dd0 + i][0])[eq];
        #pragma unroll
        for (int j = 0; j < 8; ++j) wv[j] = ((const float4*)(W + (size_t)(e20 + j) * DD))[eq];
        #pragma unroll
        for (int i = 0; i < 8; ++i)
            #pragma unroll
            for (int j = 0; j < 8; ++j)
                acc[i][j] += kvv[i].x * wv[j].x + kvv[i].y * wv[j].y
                           + kvv[i].z * wv[j].z + kvv[i].w * wv[j].w;
    }
    float* op = Mw + (size_t)h * DD * DD;
    #pragma unroll
    for (int i = 0; i < 8; ++i) {
        float4 o0 = make_float4(acc[i][0], acc[i][1], acc[i][2], acc[i][3]);
        float4 o1 = make_float4(acc[i][4], acc[i][5], acc[i][6], acc[i][7]);
        ((float4*)(op + (size_t)(dd0 + i) * DD + e20))[0] = o0;
        ((float4*)(op + (size_t)(dd0 + i) * DD + e20))[1] = o1;
    }
}

// ---------------- 4: block-sparse flash attention, bf16 MFMA ----------------
// 4 waves/block; wave = 16-query strip x all 64 keys. Swapped QK^T (S^T = K.Q^T),
// softmax near-lane-local, P via LDS, V staged transposed for contiguous B-frags.
__global__ __launch_bounds__(256, 3) void sparse_attn(
    const float* __restrict__ q, const float* __restrict__ k, const float* __restrict__ v,
    const int* __restrict__ lut, float* __restrict__ out)
{
    // XCD-affine decode: b&7 == h%8 so each XCD's L2 sees ~3 heads of K/V
    const int b = blockIdx.x;
    const int slot = b >> 3;
    const int h = (b & 7) + 8 * (slot >> 5);
    const int nq = slot & 31;

    __shared__ unsigned short Ks[BLK * DD];      // 16 KB [key][d] swizzled
    __shared__ unsigned short Vt[DD * BLK];      // 16 KB [d][key] swizzled
    __shared__ unsigned short Ps[4 * 16 * BLK];  // 8 KB per-wave [q][key] swizzled

    const int tid = threadIdx.x;
    const int wid = tid >> 6, lane = tid & 63;
    const int l15 = lane & 15, g = lane >> 4;
    const int q0 = wid * 16;

    // ---- Q fragments: scale folded in, hi/lo split, stationary in regs ----
    bf16x8 qhi[4], qlo[4];
    {
        const float scale = 0.08838834764831845f;  // D^-0.5
        const int qrow = nq * BLK + q0 + l15;
        const float* qp = q + ((size_t)qrow * HH + h) * DD;
        #pragma unroll
        for (int ks = 0; ks < 4; ++ks) {
            const int d0 = ks * 32 + g * 8;
            float4 a = *(const float4*)(qp + d0);
            float4 c = *(const float4*)(qp + d0 + 4);
            float vv[8] = {a.x, a.y, a.z, a.w, c.x, c.y, c.z, c.w};
            #pragma unroll
            for (int j = 0; j < 8; ++j) {
                float s = vv[j] * scale;
                unsigned short hi = f2bf(s);
                float lo = s - bf2f(hi);
                qhi[ks][j] = (short)hi;
                qlo[ks][j] = (short)f2bf(lo);
            }
        }
    }

    f32x4 Oacc[8];
    #pragma unroll
    for (int nt = 0; nt < 8; ++nt) Oacc[nt] = (f32x4){0.f, 0.f, 0.f, 0.f};
    float m_run = -1e30f, l_run = 0.f;

    const int* lrow = lut + ((size_t)h * NBLK + nq) * TOPK;

    for (int it = 0; it < TOPK; ++it) {
        const int kbI = lrow[it];
        __syncthreads();  // prior iteration's LDS readers done
        // ---- stage K row-major bf16 (b128 writes, chunk ^= row&7) ----
        {
            const int r = tid >> 2;
            const int dbs = (tid & 3) * 32;
            const float* kp = k + ((size_t)(kbI * BLK + r) * HH + h) * DD;
            #pragma unroll
            for (int j2 = 0; j2 < 4; ++j2) {
                const int d0 = dbs + j2 * 8;
                float4 a = *(const float4*)(kp + d0);
                float4 c = *(const float4*)(kp + d0 + 4);
                unsigned short tmp[8] = {f2bf(a.x), f2bf(a.y), f2bf(a.z), f2bf(a.w),
                                         f2bf(c.x), f2bf(c.y), f2bf(c.z), f2bf(c.w)};
                const int chunk = (d0 >> 3) ^ (r & 7);
                *(bf16x8*)&Ks[r * DD + chunk * 8] = *(bf16x8*)tmp;
            }
        }
        // ---- stage V transposed bf16 (packed key-pair b32 writes) ----
        {
            const int kp2 = tid >> 3;   // key pair 0..31
            const int dgb = tid & 7;
            const float* v0p = v + ((size_t)(kbI * BLK + kp2 * 2) * HH + h) * DD;
            const float* v1p = v0p + (size_t)HH * DD;
            #pragma unroll
            for (int j2 = 0; j2 < 4; ++j2) {
                const int d0 = dgb * 4 + j2 * 32;
                float4 a = *(const float4*)(v0p + d0);
                float4 c = *(const float4*)(v1p + d0);
                float a4[4] = {a.x, a.y, a.z, a.w}, c4[4] = {c.x, c.y, c.z, c.w};
                #pragma unroll
                for (int i = 0; i < 4; ++i) {
                    unsigned pak = (unsigned)f2bf(a4[i]) | ((unsigned)f2bf(c4[i]) << 16);
                    const int d = d0 + i;
                    const int chunk = (kp2 >> 2) ^ (d & 7);
                    *(unsigned*)&Vt[d * BLK + chunk * 8 + (kp2 & 3) * 2] = pak;
                }
            }
        }
        __syncthreads();

        // ---- S^T = K . Q^T : 2-term K*(Qhi+Qlo), one K-frag read per 2 MFMAs ----
        f32x4 sacc[4];
        #pragma unroll
        for (int mt = 0; mt < 4; ++mt) sacc[mt] = (f32x4){0.f, 0.f, 0.f, 0.f};
        #pragma unroll
        for (int ks = 0; ks < 4; ++ks) {
            #pragma unroll
            for (int mt = 0; mt < 4; ++mt) {
                const int row = mt * 16 + l15;
                const int chunk = (ks * 4 + g) ^ (row & 7);
                bf16x8 kf = *(const bf16x8*)&Ks[row * DD + chunk * 8];
                sacc[mt] = __builtin_amdgcn_mfma_f32_16x16x32_bf16(kf, qhi[ks], sacc[mt], 0, 0, 0);
                sacc[mt] = __builtin_amdgcn_mfma_f32_16x16x32_bf16(kf, qlo[ks], sacc[mt], 0, 0, 0);
            }
        }

        // ---- online softmax: lane holds 16 keys of query l15; reduce over g ----
        float sv[16];
        #pragma unroll
        for (int mt = 0; mt < 4; ++mt)
            #pragma unroll
            for (int r = 0; r < 4; ++r) sv[mt * 4 + r] = sacc[mt][r];
        float mx = -1e30f;
        #pragma unroll
        for (int i = 0; i < 16; ++i) mx = fmaxf(mx, sv[i]);
        mx = fmaxf(mx, __shfl_xor(mx, 16));
        mx = fmaxf(mx, __shfl_xor(mx, 32));
        const float mnew = fmaxf(m_run, mx);
        const float alpha = __expf(m_run - mnew);
        float ssum = 0.f;
        #pragma unroll
        for (int i = 0; i < 16; ++i) { sv[i] = __expf(sv[i] - mnew); ssum += sv[i]; }
        ssum += __shfl_xor(ssum, 16);
        ssum += __shfl_xor(ssum, 32);
        l_run = l_run * alpha + ssum;
        m_run = mnew;

        // ---- write P (own-wave region; in-wave LDS ordering, no barrier) ----
        {
            unsigned short* pw = Ps + wid * (16 * BLK) + l15 * BLK;
            #pragma unroll
            for (int mt = 0; mt < 4; ++mt) {
                #pragma unroll
                for (int pr = 0; pr < 2; ++pr) {
                    const int key = mt * 16 + g * 4 + pr * 2;
                    unsigned pak = (unsigned)f2bf(sv[mt * 4 + pr * 2])
                                 | ((unsigned)f2bf(sv[mt * 4 + pr * 2 + 1]) << 16);
                    const int chunk = (key >> 3) ^ (l15 & 7);
                    *(unsigned*)&pw[chunk * 8 + (key & 7)] = pak;
                }
            }
        }

        // ---- O rescale + PV MFMAs ----
        {
            float ar[4];
            #pragma unroll
            for (int r = 0; r < 4; ++r) ar[r] = __shfl(alpha, g * 4 + r);
            #pragma unroll
            for (int nt = 0; nt < 8; ++nt) {
                Oacc[nt][0] *= ar[0]; Oacc[nt][1] *= ar[1];
                Oacc[nt][2] *= ar[2]; Oacc[nt][3] *= ar[3];
            }
            const unsigned short* prd = Ps + wid * (16 * BLK) + l15 * BLK;
            #pragma unroll
            for (int ks2 = 0; ks2 < 2; ++ks2) {
                const int pch = (g + 4 * ks2) ^ (l15 & 7);
                bf16x8 pa = *(const bf16x8*)&prd[pch * 8];
                #pragma unroll
                for (int nt = 0; nt < 8; ++nt) {
                    const int drow = nt * 16 + l15;
                    const int vch = (g + 4 * ks2) ^ (drow & 7);
                    bf16x8 vf = *(const bf16x8*)&Vt[drow * BLK + vch * 8];
                    Oacc[nt] = __builtin_amdgcn_mfma_f32_16x16x32_bf16(pa, vf, Oacc[nt], 0, 0, 0);
                }
            }
        }
    }

    // ---- epilogue: normalize and store ----
    float linv[4];
    #pragma unroll
    for (int r = 0; r < 4; ++r) linv[r] = 1.0f / __shfl(l_run, g * 4 + r);
    #pragma unroll
    for (int r = 0; r < 4; ++r) {
        const int grow = nq * BLK + q0 + g * 4 + r;
        float* dst = out + ((size_t)grow * HH + h) * DD + l15;
        #pragma unroll
        for (int nt = 0; nt < 8; ++nt)
            dst[nt * 16] = Oacc[nt][r] * linv[r];
    }
}

// ---------------- 5: linear-attn output: out += (ql @ M)/den + b ----------------
__global__ __launch_bounds__(256) void linear_out(
    const float* __restrict__ q, const float* __restrict__ Mw,
    const float* __restrict__ ksumf, const float* __restrict__ pb,
    float* __restrict__ out)
{
    const int c = blockIdx.x, h = blockIdx.y;
    __shared__ float M_s[DD][DD];
    __shared__ float ql_s[BLK][DD];
    __shared__ float dinv_s[BLK];
    __shared__ float b_s[DD];
    const int tid = threadIdx.x;
    for (int f = tid; f < DD * DD / 4; f += 256)
        ((float4*)M_s)[f] = ((const float4*)(Mw + (size_t)h * DD * DD))[f];
    if (tid < DD) b_s[tid] = pb[tid];
    {
        const int r = tid >> 2, sg = tid & 3;
        const float* qrow = q + ((size_t)(c * BLK + r) * HH + h) * DD + sg * 32;
        float vals[32];
        float mx = -1e30f;
        #pragma unroll
        for (int u = 0; u < 32; ++u) { vals[u] = qrow[u]; mx = fmaxf(mx, vals[u]); }
        mx = fmaxf(mx, __shfl_xor(mx, 1));
        mx = fmaxf(mx, __shfl_xor(mx, 2));
        float s = 0.f;
        #pragma unroll
        for (int u = 0; u < 32; ++u) { vals[u] = __expf(vals[u] - mx); s += vals[u]; }
        s += __shfl_xor(s, 1);
        s += __shfl_xor(s, 2);
        const float rinv = 1.0f / s;
        const float* ks = ksumf + (size_t)h * DD + sg * 32;
        float den = 0.f;
        #pragma unroll
        for (int u = 0; u < 32; ++u) {
            const float ql = vals[u] * rinv;
            ql_s[r][sg * 32 + u] = ql;
            den += ql * ks[u];
        }
        den += __shfl_xor(den, 1);
        den += __shfl_xor(den, 2);
        if (sg == 0) dinv_s[r] = 1.0f / (1e-5f + den);
    }
    __syncthreads();
    const int ti = tid >> 4, tj = tid & 15;
    const int i0 = ti * 4, e0 = tj * 8;
    float acc[4][8];
    #pragma unroll
    for (int a = 0; a < 4; ++a)
        #pragma unroll
        for (int j = 0; j < 8; ++j) acc[a][j] = 0.f;
    for (int dq = 0; dq < DD / 4; ++dq) {
        float4 qv[4];
        #pragma unroll
        for (int a = 0; a < 4; ++a) qv[a] = ((const float4*)&ql_s[i0 + a][0])[dq];
        #pragma unroll
        for (int dd = 0; dd < 4; ++dd) {
            const int d = dq * 4 + dd;
            const float4 m0 = ((const float4*)&M_s[d][0])[tj * 2];
            const float4 m1 = ((const float4*)&M_s[d][0])[tj * 2 + 1];
            #pragma unroll
            for (int a = 0; a < 4; ++a) {
                const float qq = ((const float*)&qv[a])[dd];
                acc[a][0] += qq * m0.x; acc[a][1] += qq * m0.y;
                acc[a][2] += qq * m0.z; acc[a][3] += qq * m0.w;
                acc[a][4] += qq * m1.x; acc[a][5] += qq * m1.y;
                acc[a][6] += qq * m1.z; acc[a][7] += qq * m1.w;
            }
        }
    }
    #pragma unroll
    for (int a = 0; a < 4; ++a) {
        const float di = dinv_s[i0 + a];
        float* dst = out + ((size_t)(c * BLK + i0 + a) * HH + h) * DD + e0;
        float4 o0 = ((float4*)dst)[0];
        float4 o1 = ((float4*)dst)[1];
        o0.x += acc[a][0] * di + b_s[e0 + 0];
        o0.y += acc[a][1] * di + b_s[e0 + 1];
        o0.z += acc[a][2] * di + b_s[e0 + 2];
        o0.w += acc[a][3] * di + b_s[e0 + 3];
        o1.x += acc[a][4] * di + b_s[e0 + 4];
        o1.y += acc[a][5] * di + b_s[e0 + 5];
        o1.z += acc[a][6] * di + b_s[e0 + 6];
        o1.w += acc[a][7] * di + b_s[e0 + 7];
        ((float4*)dst)[0] = o0;
        ((float4*)dst)[1] = o1;
    }
}

extern "C" void kernel_launch(void* const* d_in, const int* in_sizes, int n_in,
                              void* d_out, int out_size, void* d_ws, size_t ws_size,
                              hipStream_t stream)
{
    (void)in_sizes; (void)n_in; (void)out_size; (void)ws_size;
    const float* q  = (const float*)d_in[0];
    const float* k  = (const float*)d_in[1];
    const float* v  = (const float*)d_in[2];
    const float* pw = (const float*)d_in[3];
    const float* pb = (const float*)d_in[4];
    float* out = (float*)d_out;
    char* ws = (char*)d_ws;
    size_t off = 0;
    int*   lut   = (int*)(ws + off);   off += (size_t)HH * NBLK * TOPK * 4;
    float* qb    = (float*)(ws + off); off += (size_t)HH * NBLK * DD * 4;
    float* kb    = (float*)(ws + off); off += (size_t)HH * NBLK * DD * 4;
    float* kvp   = (float*)(ws + off); off += (size_t)HH * NCHUNK * DD * DD * 4;
    float* ksp   = (float*)(ws + off); off += (size_t)HH * NCHUNK * DD * 4;
    float* Mw    = (float*)(ws + off); off += (size_t)HH * DD * DD * 4;
    float* ksumf = (float*)(ws + off); off += (size_t)HH * DD * 4;

    pool_kernel<<<dim3(NBLK, HH), 256, 0, stream>>>(q, k, qb, kb);
    topk_kernel<<<HH, 256, 0, stream>>>(qb, kb, lut);
    kv_partial<<<dim3(HH, NCHUNK), 256, 0, stream>>>(k, v, kvp, ksp);
    reduce_M<<<HH, 256, 0, stream>>>(kvp, ksp, pw, Mw, ksumf);
    sparse_attn<<<NBLK * HH, 256, 0, stream>>>(q, k, v, lut, out);
    linear_out<<<dim3(NBLK, HH), 256, 0, stream>>>(q, Mw, ksumf, pb, out);
}

// Round 3
// 187.455 us; speedup vs baseline: 3.7907x; 1.7280x over previous
//
#include <hip/hip_runtime.h>
#include <math.h>

#define HH 24
#define LLEN 2048
#define DD 128
#define BLK 64
#define NBLK 32
#define TOPK 16
#define NCHUNK 8

typedef __attribute__((ext_vector_type(8))) short bf16x8;
typedef __attribute__((ext_vector_type(4))) float f32x4;

__device__ __forceinline__ unsigned short f2bf(float f) {
    unsigned u = __builtin_bit_cast(unsigned, f);
    unsigned r = (u + 0x7FFFu + ((u >> 16) & 1u)) >> 16;
    return (unsigned short)r;
}
__device__ __forceinline__ float bf2f(unsigned short b) {
    unsigned u = ((unsigned)b) << 16;
    return __builtin_bit_cast(float, u);
}

// ---------------- 1a: block pooling (sums; ranking-invariant scale) ----------------
__global__ __launch_bounds__(256) void pool_kernel(
    const float* __restrict__ q, const float* __restrict__ k,
    float* __restrict__ qb, float* __restrict__ kb)
{
    const int nb = blockIdx.x, h = blockIdx.y;
    const int d = threadIdx.x & 127, half = threadIdx.x >> 7;
    const size_t rs = (size_t)HH * DD;
    const float* qp = q + ((size_t)(nb * BLK + half * 32) * HH + h) * DD + d;
    const float* kp = k + ((size_t)(nb * BLK + half * 32) * HH + h) * DD + d;
    float sq = 0.f, sk = 0.f;
    #pragma unroll 8
    for (int i = 0; i < 32; ++i) { sq += qp[i * rs]; sk += kp[i * rs]; }
    __shared__ float tq[2][DD], tk[2][DD];
    tq[half][d] = sq; tk[half][d] = sk;
    __syncthreads();
    if (half == 0) {
        qb[((size_t)h * NBLK + nb) * DD + d] = tq[0][d] + tq[1][d];
        kb[((size_t)h * NBLK + nb) * DD + d] = tk[0][d] + tk[1][d];
    }
}

// ---------------- 1b: block scores + top-16 LUT ----------------
__global__ __launch_bounds__(256) void topk_kernel(
    const float* __restrict__ qb, const float* __restrict__ kb, int* __restrict__ lut)
{
    const int h = blockIdx.x;
    __shared__ float kb_s[NBLK][DD];
    __shared__ float sc[NBLK][NBLK];
    const int tid = threadIdx.x;
    for (int f = tid; f < NBLK * DD / 4; f += 256)
        ((float4*)kb_s)[f] = ((const float4*)(kb + (size_t)h * NBLK * DD))[f];
    __syncthreads();
    for (int p = tid; p < NBLK * NBLK; p += 256) {
        const int iq = p >> 5, ik = p & 31;
        const float4* qr4 = (const float4*)(qb + ((size_t)h * NBLK + iq) * DD);
        const float4* kr4 = (const float4*)&kb_s[ik][0];
        float s = 0.f;
        for (int dq = 0; dq < DD / 4; ++dq) {
            float4 a = qr4[dq], b = kr4[dq];
            s += a.x * b.x + a.y * b.y + a.z * b.z + a.w * b.w;
        }
        sc[iq][ik] = s;
    }
    __syncthreads();
    if (tid < NBLK) {
        const int iq = tid;
        for (int t = 0; t < TOPK; ++t) {
            float bv = -1e30f; int bi = 0;
            for (int j = 0; j < NBLK; ++j) {
                float s = sc[iq][j];
                if (s > bv) { bv = s; bi = j; }
            }
            lut[((size_t)h * NBLK + iq) * TOPK + t] = bi;
            sc[iq][bi] = -1e30f;
        }
    }
}

// ---------------- 2: kvsum partials via MFMA ----------------
// grid (HH, NCHUNK); block = 256 thr / 4 waves; chunk = 256 rows (2 passes of 128).
// kl = row-softmax(k) and v staged TRANSPOSED bf16 in swizzled LDS; kvp[d][e] += klT . v.
__global__ __launch_bounds__(256, 2) void kv_mfma(
    const float* __restrict__ k, const float* __restrict__ v,
    float* __restrict__ kvp, float* __restrict__ ksp)
{
    const int h = blockIdx.x, c = blockIdx.y;
    __shared__ unsigned short klT[DD * DD];  // [d][l] swizzled, 32 KB
    __shared__ unsigned short vT[DD * DD];   // [e][l] swizzled, 32 KB
    const int tid = threadIdx.x;
    const int quad = tid >> 3, dpart = tid & 7;   // 32 row-quads x 8 d-parts
    const int d0 = dpart * 16;
    const int wid = tid >> 6, lane = tid & 63;
    const int l15 = lane & 15, g = lane >> 4;

    f32x4 acc[2][8];
    #pragma unroll
    for (int mi = 0; mi < 2; ++mi)
        #pragma unroll
        for (int nt = 0; nt < 8; ++nt) acc[mi][nt] = (f32x4){0.f, 0.f, 0.f, 0.f};
    float ksa[16];
    #pragma unroll
    for (int j = 0; j < 16; ++j) ksa[j] = 0.f;

    for (int pass = 0; pass < 2; ++pass) {
        const int l0 = (c * 2 + pass) * DD;
        __syncthreads();  // protect LDS from previous pass's MFMA readers
        // ---- stage kl (softmax rows) transposed ----
        {
            const int lr = quad * 4;
            float rows[4][16];
            #pragma unroll
            for (int i = 0; i < 4; ++i) {
                const float4* kp4 = (const float4*)(k + ((size_t)(l0 + lr + i) * HH + h) * DD + d0);
                #pragma unroll
                for (int t4 = 0; t4 < 4; ++t4) {
                    float4 x = kp4[t4];
                    rows[i][t4 * 4 + 0] = x.x; rows[i][t4 * 4 + 1] = x.y;
                    rows[i][t4 * 4 + 2] = x.z; rows[i][t4 * 4 + 3] = x.w;
                }
            }
            #pragma unroll
            for (int i = 0; i < 4; ++i) {
                float mx = -1e30f;
                #pragma unroll
                for (int j = 0; j < 16; ++j) mx = fmaxf(mx, rows[i][j]);
                mx = fmaxf(mx, __shfl_xor(mx, 1));
                mx = fmaxf(mx, __shfl_xor(mx, 2));
                mx = fmaxf(mx, __shfl_xor(mx, 4));
                float s = 0.f;
                #pragma unroll
                for (int j = 0; j < 16; ++j) { rows[i][j] = __expf(rows[i][j] - mx); s += rows[i][j]; }
                s += __shfl_xor(s, 1);
                s += __shfl_xor(s, 2);
                s += __shfl_xor(s, 4);
                const float rinv = 1.0f / s;
                #pragma unroll
                for (int j = 0; j < 16; ++j) { rows[i][j] *= rinv; ksa[j] += rows[i][j]; }
            }
            #pragma unroll
            for (int j = 0; j < 16; ++j) {
                const int d = d0 + j;
                unsigned long long pk =
                    (unsigned long long)f2bf(rows[0][j]) |
                    ((unsigned long long)f2bf(rows[1][j]) << 16) |
                    ((unsigned long long)f2bf(rows[2][j]) << 32) |
                    ((unsigned long long)f2bf(rows[3][j]) << 48);
                const int chunk = (quad >> 1) ^ (d & 7);
                *(unsigned long long*)&klT[d * DD + chunk * 8 + (quad & 1) * 4] = pk;
            }
        }
        // ---- stage v transposed ----
        {
            const int lr = quad * 4;
            float rows[4][16];
            #pragma unroll
            for (int i = 0; i < 4; ++i) {
                const float4* vp4 = (const float4*)(v + ((size_t)(l0 + lr + i) * HH + h) * DD + d0);
                #pragma unroll
                for (int t4 = 0; t4 < 4; ++t4) {
                    float4 x = vp4[t4];
                    rows[i][t4 * 4 + 0] = x.x; rows[i][t4 * 4 + 1] = x.y;
                    rows[i][t4 * 4 + 2] = x.z; rows[i][t4 * 4 + 3] = x.w;
                }
            }
            #pragma unroll
            for (int j = 0; j < 16; ++j) {
                const int e = d0 + j;
                unsigned long long pk =
                    (unsigned long long)f2bf(rows[0][j]) |
                    ((unsigned long long)f2bf(rows[1][j]) << 16) |
                    ((unsigned long long)f2bf(rows[2][j]) << 32) |
                    ((unsigned long long)f2bf(rows[3][j]) << 48);
                const int chunk = (quad >> 1) ^ (e & 7);
                *(unsigned long long*)&vT[e * DD + chunk * 8 + (quad & 1) * 4] = pk;
            }
        }
        __syncthreads();
        // ---- MFMA: wave owns m-tiles {2w,2w+1} x all 8 n-tiles ----
        #pragma unroll
        for (int ks = 0; ks < 4; ++ks) {
            bf16x8 af[2];
            #pragma unroll
            for (int mi = 0; mi < 2; ++mi) {
                const int d = (wid * 2 + mi) * 16 + l15;
                const int chunk = (ks * 4 + g) ^ (d & 7);
                af[mi] = *(const bf16x8*)&klT[d * DD + chunk * 8];
            }
            #pragma unroll
            for (int nt = 0; nt < 8; ++nt) {
                const int e = nt * 16 + l15;
                const int chunk = (ks * 4 + g) ^ (e & 7);
                bf16x8 bf = *(const bf16x8*)&vT[e * DD + chunk * 8];
                acc[0][nt] = __builtin_amdgcn_mfma_f32_16x16x32_bf16(af[0], bf, acc[0][nt], 0, 0, 0);
                acc[1][nt] = __builtin_amdgcn_mfma_f32_16x16x32_bf16(af[1], bf, acc[1][nt], 0, 0, 0);
            }
        }
    }
    // ---- store D x D partial ----
    float* op = kvp + ((size_t)h * NCHUNK + c) * DD * DD;
    #pragma unroll
    for (int mi = 0; mi < 2; ++mi)
        #pragma unroll
        for (int nt = 0; nt < 8; ++nt)
            #pragma unroll
            for (int r = 0; r < 4; ++r)
                op[(size_t)((wid * 2 + mi) * 16 + g * 4 + r) * DD + nt * 16 + l15] = acc[mi][nt][r];
    // ---- ksum partial: reduce across the 8 quads of this wave ----
    #pragma unroll
    for (int j = 0; j < 16; ++j) {
        ksa[j] += __shfl_xor(ksa[j], 8);
        ksa[j] += __shfl_xor(ksa[j], 16);
        ksa[j] += __shfl_xor(ksa[j], 32);
    }
    if ((lane >> 3) == 0) {
        float* kp2 = ksp + (((size_t)h * NCHUNK + c) * 4 + wid) * DD + d0;
        #pragma unroll
        for (int j = 0; j < 16; ++j) kp2[j] = ksa[j];
    }
}

// ---------------- 3: reduce partials; Mt = (kvsum @ W^T)^T in bf16; final ksum ----------------
__global__ __launch_bounds__(256) void reduce_M(
    const float* __restrict__ kvp, const float* __restrict__ ksp,
    const float* __restrict__ W, unsigned short* __restrict__ Mt,
    float* __restrict__ ksumf)
{
    const int h = blockIdx.x, rb = blockIdx.y;  // rows d in [rb*32, rb*32+32)
    __shared__ float kv_s[32][DD];              // 16 KB
    const int tid = threadIdx.x;
    for (int f4 = tid; f4 < 32 * DD / 4; f4 += 256) {
        float4 s = make_float4(0.f, 0.f, 0.f, 0.f);
        #pragma unroll
        for (int cc = 0; cc < NCHUNK; ++cc) {
            float4 x = ((const float4*)(kvp + ((size_t)h * NCHUNK + cc) * DD * DD
                                        + (size_t)rb * 32 * DD))[f4];
            s.x += x.x; s.y += x.y; s.z += x.z; s.w += x.w;
        }
        ((float4*)kv_s)[f4] = s;
    }
    if (rb == 0 && tid < DD) {
        float s = 0.f;
        #pragma unroll
        for (int p = 0; p < NCHUNK * 4; ++p)
            s += ksp[((size_t)h * NCHUNK * 4 + p) * DD + tid];
        ksumf[(size_t)h * DD + tid] = s;
    }
    __syncthreads();
    const int e = tid & 127, dh = tid >> 7;
    float accm[16];
    #pragma unroll
    for (int i = 0; i < 16; ++i) accm[i] = 0.f;
    const float4* wr4 = (const float4*)(W + (size_t)e * DD);
    for (int c4 = 0; c4 < DD / 4; ++c4) {
        const float4 wv = wr4[c4];
        #pragma unroll
        for (int i = 0; i < 16; ++i) {
            const float4 kv4 = ((const float4*)&kv_s[dh * 16 + i][0])[c4];
            accm[i] += kv4.x * wv.x + kv4.y * wv.y + kv4.z * wv.z + kv4.w * wv.w;
        }
    }
    unsigned short* mp = Mt + (size_t)h * DD * DD + (size_t)e * DD + rb * 32 + dh * 16;
    #pragma unroll
    for (int ii = 0; ii < 16; ii += 2) {
        unsigned pk = (unsigned)f2bf(accm[ii]) | ((unsigned)f2bf(accm[ii + 1]) << 16);
        *(unsigned*)&mp[ii] = pk;
    }
}

// ---------------- 4: block-sparse flash attention, bf16 MFMA (unchanged) ----------------
__global__ __launch_bounds__(256, 3) void sparse_attn(
    const float* __restrict__ q, const float* __restrict__ k, const float* __restrict__ v,
    const int* __restrict__ lut, float* __restrict__ out)
{
    const int b = blockIdx.x;
    const int slot = b >> 3;
    const int h = (b & 7) + 8 * (slot >> 5);
    const int nq = slot & 31;

    __shared__ unsigned short Ks[BLK * DD];
    __shared__ unsigned short Vt[DD * BLK];
    __shared__ unsigned short Ps[4 * 16 * BLK];

    const int tid = threadIdx.x;
    const int wid = tid >> 6, lane = tid & 63;
    const int l15 = lane & 15, g = lane >> 4;
    const int q0 = wid * 16;

    bf16x8 qhi[4], qlo[4];
    {
        const float scale = 0.08838834764831845f;
        const int qrow = nq * BLK + q0 + l15;
        const float* qp = q + ((size_t)qrow * HH + h) * DD;
        #pragma unroll
        for (int ks = 0; ks < 4; ++ks) {
            const int d0 = ks * 32 + g * 8;
            float4 a = *(const float4*)(qp + d0);
            float4 c = *(const float4*)(qp + d0 + 4);
            float vv[8] = {a.x, a.y, a.z, a.w, c.x, c.y, c.z, c.w};
            #pragma unroll
            for (int j = 0; j < 8; ++j) {
                float s = vv[j] * scale;
                unsigned short hi = f2bf(s);
                float lo = s - bf2f(hi);
                qhi[ks][j] = (short)hi;
                qlo[ks][j] = (short)f2bf(lo);
            }
        }
    }

    f32x4 Oacc[8];
    #pragma unroll
    for (int nt = 0; nt < 8; ++nt) Oacc[nt] = (f32x4){0.f, 0.f, 0.f, 0.f};
    float m_run = -1e30f, l_run = 0.f;

    const int* lrow = lut + ((size_t)h * NBLK + nq) * TOPK;

    for (int it = 0; it < TOPK; ++it) {
        const int kbI = lrow[it];
        __syncthreads();
        {
            const int r = tid >> 2;
            const int dbs = (tid & 3) * 32;
            const float* kp = k + ((size_t)(kbI * BLK + r) * HH + h) * DD;
            #pragma unroll
            for (int j2 = 0; j2 < 4; ++j2) {
                const int d0 = dbs + j2 * 8;
                float4 a = *(const float4*)(kp + d0);
                float4 c = *(const float4*)(kp + d0 + 4);
                unsigned short tmp[8] = {f2bf(a.x), f2bf(a.y), f2bf(a.z), f2bf(a.w),
                                         f2bf(c.x), f2bf(c.y), f2bf(c.z), f2bf(c.w)};
                const int chunk = (d0 >> 3) ^ (r & 7);
                *(bf16x8*)&Ks[r * DD + chunk * 8] = *(bf16x8*)tmp;
            }
        }
        {
            const int kp2 = tid >> 3;
            const int dgb = tid & 7;
            const float* v0p = v + ((size_t)(kbI * BLK + kp2 * 2) * HH + h) * DD;
            const float* v1p = v0p + (size_t)HH * DD;
            #pragma unroll
            for (int j2 = 0; j2 < 4; ++j2) {
                const int d0 = dgb * 4 + j2 * 32;
                float4 a = *(const float4*)(v0p + d0);
                float4 c = *(const float4*)(v1p + d0);
                float a4[4] = {a.x, a.y, a.z, a.w}, c4[4] = {c.x, c.y, c.z, c.w};
                #pragma unroll
                for (int i = 0; i < 4; ++i) {
                    unsigned pak = (unsigned)f2bf(a4[i]) | ((unsigned)f2bf(c4[i]) << 16);
                    const int d = d0 + i;
                    const int chunk = (kp2 >> 2) ^ (d & 7);
                    *(unsigned*)&Vt[d * BLK + chunk * 8 + (kp2 & 3) * 2] = pak;
                }
            }
        }
        __syncthreads();

        f32x4 sacc[4];
        #pragma unroll
        for (int mt = 0; mt < 4; ++mt) sacc[mt] = (f32x4){0.f, 0.f, 0.f, 0.f};
        #pragma unroll
        for (int ks = 0; ks < 4; ++ks) {
            #pragma unroll
            for (int mt = 0; mt < 4; ++mt) {
                const int row = mt * 16 + l15;
                const int chunk = (ks * 4 + g) ^ (row & 7);
                bf16x8 kf = *(const bf16x8*)&Ks[row * DD + chunk * 8];
                sacc[mt] = __builtin_amdgcn_mfma_f32_16x16x32_bf16(kf, qhi[ks], sacc[mt], 0, 0, 0);
                sacc[mt] = __builtin_amdgcn_mfma_f32_16x16x32_bf16(kf, qlo[ks], sacc[mt], 0, 0, 0);
            }
        }

        float sv[16];
        #pragma unroll
        for (int mt = 0; mt < 4; ++mt)
            #pragma unroll
            for (int r = 0; r < 4; ++r) sv[mt * 4 + r] = sacc[mt][r];
        float mx = -1e30f;
        #pragma unroll
        for (int i = 0; i < 16; ++i) mx = fmaxf(mx, sv[i]);
        mx = fmaxf(mx, __shfl_xor(mx, 16));
        mx = fmaxf(mx, __shfl_xor(mx, 32));
        const float mnew = fmaxf(m_run, mx);
        const float alpha = __expf(m_run - mnew);
        float ssum = 0.f;
        #pragma unroll
        for (int i = 0; i < 16; ++i) { sv[i] = __expf(sv[i] - mnew); ssum += sv[i]; }
        ssum += __shfl_xor(ssum, 16);
        ssum += __shfl_xor(ssum, 32);
        l_run = l_run * alpha + ssum;
        m_run = mnew;

        {
            unsigned short* pw = Ps + wid * (16 * BLK) + l15 * BLK;
            #pragma unroll
            for (int mt = 0; mt < 4; ++mt) {
                #pragma unroll
                for (int pr = 0; pr < 2; ++pr) {
                    const int key = mt * 16 + g * 4 + pr * 2;
                    unsigned pak = (unsigned)f2bf(sv[mt * 4 + pr * 2])
                                 | ((unsigned)f2bf(sv[mt * 4 + pr * 2 + 1]) << 16);
                    const int chunk = (key >> 3) ^ (l15 & 7);
                    *(unsigned*)&pw[chunk * 8 + (key & 7)] = pak;
                }
            }
        }

        {
            float ar[4];
            #pragma unroll
            for (int r = 0; r < 4; ++r) ar[r] = __shfl(alpha, g * 4 + r);
            #pragma unroll
            for (int nt = 0; nt < 8; ++nt) {
                Oacc[nt][0] *= ar[0]; Oacc[nt][1] *= ar[1];
                Oacc[nt][2] *= ar[2]; Oacc[nt][3] *= ar[3];
            }
            const unsigned short* prd = Ps + wid * (16 * BLK) + l15 * BLK;
            #pragma unroll
            for (int ks2 = 0; ks2 < 2; ++ks2) {
                const int pch = (g + 4 * ks2) ^ (l15 & 7);
                bf16x8 pa = *(const bf16x8*)&prd[pch * 8];
                #pragma unroll
                for (int nt = 0; nt < 8; ++nt) {
                    const int drow = nt * 16 + l15;
                    const int vch = (g + 4 * ks2) ^ (drow & 7);
                    bf16x8 vf = *(const bf16x8*)&Vt[drow * BLK + vch * 8];
                    Oacc[nt] = __builtin_amdgcn_mfma_f32_16x16x32_bf16(pa, vf, Oacc[nt], 0, 0, 0);
                }
            }
        }
    }

    float linv[4];
    #pragma unroll
    for (int r = 0; r < 4; ++r) linv[r] = 1.0f / __shfl(l_run, g * 4 + r);
    #pragma unroll
    for (int r = 0; r < 4; ++r) {
        const int grow = nq * BLK + q0 + g * 4 + r;
        float* dst = out + ((size_t)grow * HH + h) * DD + l15;
        #pragma unroll
        for (int nt = 0; nt < 8; ++nt)
            dst[nt * 16] = Oacc[nt][r] * linv[r];
    }
}

// ---------------- 5: linear-attn output via MFMA: out += (ql @ M)/den + b ----------------
__global__ __launch_bounds__(256, 2) void linear_out(
    const float* __restrict__ q, const unsigned short* __restrict__ Mt,
    const float* __restrict__ ksumf, const float* __restrict__ pb,
    float* __restrict__ out)
{
    const int c = blockIdx.x, h = blockIdx.y;
    __shared__ unsigned short Ms[DD * DD];  // [e][d] swizzled, 32 KB
    __shared__ float b_s[DD];
    const int tid = threadIdx.x;
    const int wid = tid >> 6, lane = tid & 63;
    const int l15 = lane & 15, g = lane >> 4;

    const unsigned short* msrc = Mt + (size_t)h * DD * DD;
    for (int f = tid; f < DD * DD / 8; f += 256) {
        const int e = f >> 4, seg = f & 15;
        bf16x8 val = *(const bf16x8*)(msrc + (size_t)e * DD + seg * 8);
        const int chunk = seg ^ (e & 7);
        *(bf16x8*)&Ms[e * DD + chunk * 8] = val;
    }
    if (tid < DD) b_s[tid] = pb[tid];

    // ql softmax: row l handled by 4 lanes (g = d-chunk), A-fragment layout
    const int l = c * BLK + wid * 16 + l15;
    const float* qp = q + ((size_t)l * HH + h) * DD;
    float qv[32];
    float mx = -1e30f;
    #pragma unroll
    for (int ks = 0; ks < 4; ++ks) {
        const int dd0 = ks * 32 + g * 8;
        float4 a = *(const float4*)(qp + dd0);
        float4 b2 = *(const float4*)(qp + dd0 + 4);
        qv[ks * 8 + 0] = a.x;  qv[ks * 8 + 1] = a.y;
        qv[ks * 8 + 2] = a.z;  qv[ks * 8 + 3] = a.w;
        qv[ks * 8 + 4] = b2.x; qv[ks * 8 + 5] = b2.y;
        qv[ks * 8 + 6] = b2.z; qv[ks * 8 + 7] = b2.w;
    }
    #pragma unroll
    for (int j = 0; j < 32; ++j) mx = fmaxf(mx, qv[j]);
    mx = fmaxf(mx, __shfl_xor(mx, 16));
    mx = fmaxf(mx, __shfl_xor(mx, 32));
    float s = 0.f;
    #pragma unroll
    for (int j = 0; j < 32; ++j) { qv[j] = __expf(qv[j] - mx); s += qv[j]; }
    s += __shfl_xor(s, 16);
    s += __shfl_xor(s, 32);
    const float rinv = 1.0f / s;
    float den = 0.f;
    bf16x8 af[4];
    const float* ksb = ksumf + (size_t)h * DD;
    #pragma unroll
    for (int ks = 0; ks < 4; ++ks) {
        const int dd0 = ks * 32 + g * 8;
        float4 k0 = *(const float4*)(ksb + dd0);
        float4 k1 = *(const float4*)(ksb + dd0 + 4);
        float kk[8] = {k0.x, k0.y, k0.z, k0.w, k1.x, k1.y, k1.z, k1.w};
        #pragma unroll
        for (int j = 0; j < 8; ++j) {
            const float ql = qv[ks * 8 + j] * rinv;
            af[ks][j] = (short)f2bf(ql);
            den += ql * kk[j];
        }
    }
    den += __shfl_xor(den, 16);
    den += __shfl_xor(den, 32);
    const float dinv = 1.0f / (1e-5f + den);
    __syncthreads();

    f32x4 acc[8];
    #pragma unroll
    for (int nt = 0; nt < 8; ++nt) acc[nt] = (f32x4){0.f, 0.f, 0.f, 0.f};
    #pragma unroll
    for (int ks = 0; ks < 4; ++ks) {
        #pragma unroll
        for (int nt = 0; nt < 8; ++nt) {
            const int e = nt * 16 + l15;
            const int chunk = (ks * 4 + g) ^ (e & 7);
            bf16x8 bf = *(const bf16x8*)&Ms[e * DD + chunk * 8];
            acc[nt] = __builtin_amdgcn_mfma_f32_16x16x32_bf16(af[ks], bf, acc[nt], 0, 0, 0);
        }
    }
    #pragma unroll
    for (int r = 0; r < 4; ++r) {
        const float di = __shfl(dinv, g * 4 + r);
        const int row = c * BLK + wid * 16 + g * 4 + r;
        float* dst = out + ((size_t)row * HH + h) * DD + l15;
        #pragma unroll
        for (int nt = 0; nt < 8; ++nt)
            dst[nt * 16] += acc[nt][r] * di + b_s[nt * 16 + l15];
    }
}

extern "C" void kernel_launch(void* const* d_in, const int* in_sizes, int n_in,
                              void* d_out, int out_size, void* d_ws, size_t ws_size,
                              hipStream_t stream)
{
    (void)in_sizes; (void)n_in; (void)out_size; (void)ws_size;
    const float* q  = (const float*)d_in[0];
    const float* k  = (const float*)d_in[1];
    const float* v  = (const float*)d_in[2];
    const float* pw = (const float*)d_in[3];
    const float* pb = (const float*)d_in[4];
    float* out = (float*)d_out;
    char* ws = (char*)d_ws;
    size_t off = 0;
    int*   lut   = (int*)(ws + off);   off += (size_t)HH * NBLK * TOPK * 4;
    float* qb    = (float*)(ws + off); off += (size_t)HH * NBLK * DD * 4;
    float* kb    = (float*)(ws + off); off += (size_t)HH * NBLK * DD * 4;
    float* kvp   = (float*)(ws + off); off += (size_t)HH * NCHUNK * DD * DD * 4;
    float* ksp   = (float*)(ws + off); off += (size_t)HH * NCHUNK * 4 * DD * 4;
    unsigned short* Mt = (unsigned short*)(ws + off); off += (size_t)HH * DD * DD * 2;
    float* ksumf = (float*)(ws + off); off += (size_t)HH * DD * 4;

    pool_kernel<<<dim3(NBLK, HH), 256, 0, stream>>>(q, k, qb, kb);
    topk_kernel<<<HH, 256, 0, stream>>>(qb, kb, lut);
    kv_mfma<<<dim3(HH, NCHUNK), 256, 0, stream>>>(k, v, kvp, ksp);
    reduce_M<<<dim3(HH, 4), 256, 0, stream>>>(kvp, ksp, pw, Mt, ksumf);
    sparse_attn<<<NBLK * HH, 256, 0, stream>>>(q, k, v, lut, out);
    linear_out<<<dim3(NBLK, HH), 256, 0, stream>>>(q, Mt, ksumf, pb, out);
}

// Round 4
// 153.936 us; speedup vs baseline: 4.6161x; 1.2177x over previous
//
#include <hip/hip_runtime.h>
#include <math.h>

#define HH 24
#define LLEN 2048
#define DD 128
#define BLK 64
#define NBLK 32
#define TOPK 16
#define NCHUNK 16

typedef __attribute__((ext_vector_type(8))) short bf16x8;
typedef __attribute__((ext_vector_type(4))) float f32x4;

typedef unsigned int u32_g __attribute__((address_space(1)));
typedef unsigned int u32_l __attribute__((address_space(3)));

__device__ __forceinline__ unsigned short f2bf(float f) {
    unsigned u = __builtin_bit_cast(unsigned, f);
    unsigned r = (u + 0x7FFFu + ((u >> 16) & 1u)) >> 16;
    return (unsigned short)r;
}
__device__ __forceinline__ float bf2f(unsigned short b) {
    unsigned u = ((unsigned)b) << 16;
    return __builtin_bit_cast(float, u);
}
// async 16B/lane global->LDS: lds base is WAVE-UNIFORM (lane0); HW adds lane*16.
__device__ __forceinline__ void gload16(unsigned short* lds, const unsigned short* g) {
    __builtin_amdgcn_global_load_lds((const u32_g*)g, (u32_l*)lds, 16, 0, 0);
}

// ---------------- 1: convert K/V to bf16 (pre-swizzled) + block pooling ----------------
// kb16[h][l][chunk^(l&7)] row-major bf16; vt16[h][ktile][d][keychunk^(d&7)] transposed bf16.
__global__ __launch_bounds__(256) void convert_pool(
    const float* __restrict__ q, const float* __restrict__ k, const float* __restrict__ v,
    unsigned short* __restrict__ kb16, unsigned short* __restrict__ vt16,
    float* __restrict__ qb, float* __restrict__ kb)
{
    const int nb = blockIdx.x, h = blockIdx.y;
    const int l0 = nb * BLK;
    const int tid = threadIdx.x;
    __shared__ unsigned short vt_s[DD * BLK];  // 16 KB

    // ---- K convert: thread = (row r, 32-d slice), swizzled row writes ----
    {
        const int r = tid >> 2, c0 = (tid & 3) * 4;  // c0..c0+3 chunks of 8
        const float* kp = k + ((size_t)(l0 + r) * HH + h) * DD + c0 * 8;
        unsigned short* krow = kb16 + ((size_t)h * LLEN + l0 + r) * DD;
        #pragma unroll
        for (int j = 0; j < 4; ++j) {
            float4 a = *(const float4*)(kp + j * 8);
            float4 c = *(const float4*)(kp + j * 8 + 4);
            unsigned short tmp[8] = {f2bf(a.x), f2bf(a.y), f2bf(a.z), f2bf(a.w),
                                     f2bf(c.x), f2bf(c.y), f2bf(c.z), f2bf(c.w)};
            const int chunk = (c0 + j) ^ (r & 7);
            *(bf16x8*)&krow[chunk * 8] = *(bf16x8*)tmp;
        }
    }
    // ---- V transpose via LDS bounce (packed key-pair u32 writes) ----
    {
        const int kp2 = tid >> 3, dgb = tid & 7;
        const float* v0p = v + ((size_t)(l0 + kp2 * 2) * HH + h) * DD;
        const float* v1p = v0p + (size_t)HH * DD;
        #pragma unroll
        for (int j2 = 0; j2 < 4; ++j2) {
            const int d0 = dgb * 4 + j2 * 32;
            float4 a = *(const float4*)(v0p + d0);
            float4 c = *(const float4*)(v1p + d0);
            float a4[4] = {a.x, a.y, a.z, a.w}, c4[4] = {c.x, c.y, c.z, c.w};
            #pragma unroll
            for (int i = 0; i < 4; ++i) {
                unsigned pak = (unsigned)f2bf(a4[i]) | ((unsigned)f2bf(c4[i]) << 16);
                const int d = d0 + i;
                const int chunk = (kp2 >> 2) ^ (d & 7);
                *(unsigned*)&vt_s[d * BLK + chunk * 8 + (kp2 & 3) * 2] = pak;
            }
        }
    }
    __syncthreads();
    {
        bf16x8* dstv = (bf16x8*)(vt16 + (size_t)(h * NBLK + nb) * DD * BLK);
        const bf16x8* srcv = (const bf16x8*)vt_s;
        #pragma unroll
        for (int j = 0; j < 4; ++j) dstv[tid * 4 + j] = srcv[tid * 4 + j];
    }
    __syncthreads();
    // ---- block-sum pooling for top-k (sums; ranking-invariant scale) ----
    {
        float* ps = (float*)vt_s;
        const int d = tid & 127, half = tid >> 7;
        const size_t rs = (size_t)HH * DD;
        const float* qp = q + ((size_t)(l0 + half * 32) * HH + h) * DD + d;
        const float* kp = k + ((size_t)(l0 + half * 32) * HH + h) * DD + d;
        float sq = 0.f, sk = 0.f;
        #pragma unroll 8
        for (int i = 0; i < 32; ++i) { sq += qp[i * rs]; sk += kp[i * rs]; }
        ps[half * 128 + d] = sq;
        ps[256 + half * 128 + d] = sk;
        __syncthreads();
        if (half == 0) {
            qb[((size_t)h * NBLK + nb) * DD + d] = ps[d] + ps[128 + d];
            kb[((size_t)h * NBLK + nb) * DD + d] = ps[256 + d] + ps[384 + d];
        }
    }
}

// ---------------- 1b: block scores + top-16 LUT ----------------
__global__ __launch_bounds__(256) void topk_kernel(
    const float* __restrict__ qb, const float* __restrict__ kb, int* __restrict__ lut)
{
    const int h = blockIdx.x;
    __shared__ float kb_s[NBLK][DD];
    __shared__ float sc[NBLK][NBLK];
    const int tid = threadIdx.x;
    for (int f = tid; f < NBLK * DD / 4; f += 256)
        ((float4*)kb_s)[f] = ((const float4*)(kb + (size_t)h * NBLK * DD))[f];
    __syncthreads();
    for (int p = tid; p < NBLK * NBLK; p += 256) {
        const int iq = p >> 5, ik = p & 31;
        const float4* qr4 = (const float4*)(qb + ((size_t)h * NBLK + iq) * DD);
        const float4* kr4 = (const float4*)&kb_s[ik][0];
        float s = 0.f;
        for (int dq = 0; dq < DD / 4; ++dq) {
            float4 a = qr4[dq], b = kr4[dq];
            s += a.x * b.x + a.y * b.y + a.z * b.z + a.w * b.w;
        }
        sc[iq][ik] = s;
    }
    __syncthreads();
    if (tid < NBLK) {
        const int iq = tid;
        for (int t = 0; t < TOPK; ++t) {
            float bv = -1e30f; int bi = 0;
            for (int j = 0; j < NBLK; ++j) {
                float s = sc[iq][j];
                if (s > bv) { bv = s; bi = j; }
            }
            lut[((size_t)h * NBLK + iq) * TOPK + t] = bi;
            sc[iq][bi] = -1e30f;
        }
    }
}

// ---------------- 2: kvsum partials via MFMA (128 rows per block) ----------------
__global__ __launch_bounds__(256, 2) void kv_mfma(
    const float* __restrict__ k, const unsigned short* __restrict__ vt16,
    float* __restrict__ kvp, float* __restrict__ ksp)
{
    const int h = blockIdx.x, c = blockIdx.y;
    __shared__ unsigned short klT[DD * DD];  // [d][l] swizzled, 32 KB
    const int tid = threadIdx.x;
    const int quad = tid >> 3, dpart = tid & 7;
    const int d0 = dpart * 16;
    const int wid = tid >> 6, lane = tid & 63;
    const int l15 = lane & 15, g = lane >> 4;

    f32x4 acc[2][8];
    #pragma unroll
    for (int mi = 0; mi < 2; ++mi)
        #pragma unroll
        for (int nt = 0; nt < 8; ++nt) acc[mi][nt] = (f32x4){0.f, 0.f, 0.f, 0.f};
    float ksa[16];
    #pragma unroll
    for (int j = 0; j < 16; ++j) ksa[j] = 0.f;

    const int l0 = c * DD;
    // ---- kl = row-softmax(k), staged transposed ----
    {
        const int lr = quad * 4;
        float rows[4][16];
        #pragma unroll
        for (int i = 0; i < 4; ++i) {
            const float4* kp4 = (const float4*)(k + ((size_t)(l0 + lr + i) * HH + h) * DD + d0);
            #pragma unroll
            for (int t4 = 0; t4 < 4; ++t4) {
                float4 x = kp4[t4];
                rows[i][t4 * 4 + 0] = x.x; rows[i][t4 * 4 + 1] = x.y;
                rows[i][t4 * 4 + 2] = x.z; rows[i][t4 * 4 + 3] = x.w;
            }
        }
        #pragma unroll
        for (int i = 0; i < 4; ++i) {
            float mx = -1e30f;
            #pragma unroll
            for (int j = 0; j < 16; ++j) mx = fmaxf(mx, rows[i][j]);
            mx = fmaxf(mx, __shfl_xor(mx, 1));
            mx = fmaxf(mx, __shfl_xor(mx, 2));
            mx = fmaxf(mx, __shfl_xor(mx, 4));
            float s = 0.f;
            #pragma unroll
            for (int j = 0; j < 16; ++j) { rows[i][j] = __expf(rows[i][j] - mx); s += rows[i][j]; }
            s += __shfl_xor(s, 1);
            s += __shfl_xor(s, 2);
            s += __shfl_xor(s, 4);
            const float rinv = 1.0f / s;
            #pragma unroll
            for (int j = 0; j < 16; ++j) { rows[i][j] *= rinv; ksa[j] += rows[i][j]; }
        }
        #pragma unroll
        for (int j = 0; j < 16; ++j) {
            const int d = d0 + j;
            unsigned long long pk =
                (unsigned long long)f2bf(rows[0][j]) |
                ((unsigned long long)f2bf(rows[1][j]) << 16) |
                ((unsigned long long)f2bf(rows[2][j]) << 32) |
                ((unsigned long long)f2bf(rows[3][j]) << 48);
            const int chunk = (quad >> 1) ^ (d & 7);
            *(unsigned long long*)&klT[d * DD + chunk * 8 + (quad & 1) * 4] = pk;
        }
    }
    __syncthreads();
    // ---- MFMA: A from klT LDS, B direct from global vt16 (L2-hot) ----
    const int bkt = c * 2;
    #pragma unroll
    for (int ks = 0; ks < 4; ++ks) {
        bf16x8 af[2];
        #pragma unroll
        for (int mi = 0; mi < 2; ++mi) {
            const int d = (wid * 2 + mi) * 16 + l15;
            const int chunk = (ks * 4 + g) ^ (d & 7);
            af[mi] = *(const bf16x8*)&klT[d * DD + chunk * 8];
        }
        const int s = ks * 4 + g;
        const int kt = bkt + (s >> 3);
        #pragma unroll
        for (int nt = 0; nt < 8; ++nt) {
            const int e = nt * 16 + l15;
            const int cc = (s & 7) ^ (e & 7);
            bf16x8 bf = *(const bf16x8*)&vt16[((size_t)(h * NBLK + kt) * DD + e) * BLK + cc * 8];
            acc[0][nt] = __builtin_amdgcn_mfma_f32_16x16x32_bf16(af[0], bf, acc[0][nt], 0, 0, 0);
            acc[1][nt] = __builtin_amdgcn_mfma_f32_16x16x32_bf16(af[1], bf, acc[1][nt], 0, 0, 0);
        }
    }
    float* op = kvp + ((size_t)h * NCHUNK + c) * DD * DD;
    #pragma unroll
    for (int mi = 0; mi < 2; ++mi)
        #pragma unroll
        for (int nt = 0; nt < 8; ++nt)
            #pragma unroll
            for (int r = 0; r < 4; ++r)
                op[(size_t)((wid * 2 + mi) * 16 + g * 4 + r) * DD + nt * 16 + l15] = acc[mi][nt][r];
    #pragma unroll
    for (int j = 0; j < 16; ++j) {
        ksa[j] += __shfl_xor(ksa[j], 8);
        ksa[j] += __shfl_xor(ksa[j], 16);
        ksa[j] += __shfl_xor(ksa[j], 32);
    }
    if ((lane >> 3) == 0) {
        float* kp2 = ksp + (((size_t)h * NCHUNK + c) * 4 + wid) * DD + d0;
        #pragma unroll
        for (int j = 0; j < 16; ++j) kp2[j] = ksa[j];
    }
}

// ---------------- 3: reduce partials; Mt = (kvsum @ W^T)^T in bf16; final ksum ----------------
__global__ __launch_bounds__(256) void reduce_M(
    const float* __restrict__ kvp, const float* __restrict__ ksp,
    const float* __restrict__ W, unsigned short* __restrict__ Mt,
    float* __restrict__ ksumf)
{
    const int h = blockIdx.x, rb = blockIdx.y;
    __shared__ float kv_s[32][DD];
    const int tid = threadIdx.x;
    for (int f4 = tid; f4 < 32 * DD / 4; f4 += 256) {
        float4 s = make_float4(0.f, 0.f, 0.f, 0.f);
        #pragma unroll
        for (int cc = 0; cc < NCHUNK; ++cc) {
            float4 x = ((const float4*)(kvp + ((size_t)h * NCHUNK + cc) * DD * DD
                                        + (size_t)rb * 32 * DD))[f4];
            s.x += x.x; s.y += x.y; s.z += x.z; s.w += x.w;
        }
        ((float4*)kv_s)[f4] = s;
    }
    if (rb == 0 && tid < DD) {
        float s = 0.f;
        #pragma unroll
        for (int p = 0; p < NCHUNK * 4; ++p)
            s += ksp[((size_t)h * NCHUNK * 4 + p) * DD + tid];
        ksumf[(size_t)h * DD + tid] = s;
    }
    __syncthreads();
    const int e = tid & 127, dh = tid >> 7;
    float accm[16];
    #pragma unroll
    for (int i = 0; i < 16; ++i) accm[i] = 0.f;
    const float4* wr4 = (const float4*)(W + (size_t)e * DD);
    for (int c4 = 0; c4 < DD / 4; ++c4) {
        const float4 wv = wr4[c4];
        #pragma unroll
        for (int i = 0; i < 16; ++i) {
            const float4 kv4 = ((const float4*)&kv_s[dh * 16 + i][0])[c4];
            accm[i] += kv4.x * wv.x + kv4.y * wv.y + kv4.z * wv.z + kv4.w * wv.w;
        }
    }
    unsigned short* mp = Mt + (size_t)h * DD * DD + (size_t)e * DD + rb * 32 + dh * 16;
    #pragma unroll
    for (int ii = 0; ii < 16; ii += 2) {
        unsigned pk = (unsigned)f2bf(accm[ii]) | ((unsigned)f2bf(accm[ii + 1]) << 16);
        *(unsigned*)&mp[ii] = pk;
    }
}

// ---------------- 4: fused block-sparse flash attention + linear-attn epilogue ----------------
// Double-buffered async global->LDS staging from pre-swizzled bf16 buffers; 1 barrier/iter.
__global__ __launch_bounds__(256, 2) void sla_attn(
    const float* __restrict__ q, const unsigned short* __restrict__ kb16,
    const unsigned short* __restrict__ vt16, const int* __restrict__ lut,
    const unsigned short* __restrict__ Mt, const float* __restrict__ ksumf,
    const float* __restrict__ pb, float* __restrict__ out)
{
    const int b = blockIdx.x;
    const int slot = b >> 3;
    const int h = (b & 7) + 8 * (slot >> 5);
    const int nq = slot & 31;

    __shared__ unsigned short Ks[2][BLK * DD];   // 2 x 16 KB
    __shared__ unsigned short Vt[2][DD * BLK];   // 2 x 16 KB
    __shared__ unsigned short Ps[4 * 16 * BLK];  // 8 KB

    const int tid = threadIdx.x;
    const int wid = tid >> 6, lane = tid & 63;
    const int l15 = lane & 15, g = lane >> 4;
    const int q0 = wid * 16;

    // ---- Q fragments: scale folded, hi/lo split, stationary ----
    bf16x8 qhi[4], qlo[4];
    {
        const float scale = 0.08838834764831845f;
        const int qrow = nq * BLK + q0 + l15;
        const float* qp = q + ((size_t)qrow * HH + h) * DD;
        #pragma unroll
        for (int ks = 0; ks < 4; ++ks) {
            const int d0 = ks * 32 + g * 8;
            float4 a = *(const float4*)(qp + d0);
            float4 c = *(const float4*)(qp + d0 + 4);
            float vv[8] = {a.x, a.y, a.z, a.w, c.x, c.y, c.z, c.w};
            #pragma unroll
            for (int j = 0; j < 8; ++j) {
                float s = vv[j] * scale;
                unsigned short hi = f2bf(s);
                float lo = s - bf2f(hi);
                qhi[ks][j] = (short)hi;
                qlo[ks][j] = (short)f2bf(lo);
            }
        }
    }

    f32x4 Oacc[8];
    #pragma unroll
    for (int nt = 0; nt < 8; ++nt) Oacc[nt] = (f32x4){0.f, 0.f, 0.f, 0.f};
    float m_run = -1e30f, l_run = 0.f;

    const int* lrow = lut + ((size_t)h * NBLK + nq) * TOPK;

    // prologue: stage tile 0 into buf 0 (wave w does issues 4w..4w+3 of K and V)
    {
        const int kbI = lrow[0];
        const unsigned short* kg = kb16 + ((size_t)h * LLEN + (size_t)kbI * BLK) * DD;
        const unsigned short* vg = vt16 + (size_t)(h * NBLK + kbI) * DD * BLK;
        #pragma unroll
        for (int i = 0; i < 4; ++i) {
            const int is = wid * 4 + i;
            gload16(&Ks[0][is * 512], kg + is * 512 + lane * 8);
            gload16(&Vt[0][is * 512], vg + is * 512 + lane * 8);
        }
    }
    __syncthreads();

    for (int it = 0; it < TOPK; ++it) {
        const int cur = it & 1;
        // ---- prefetch next tile into the other buffer (consumed at it-1; barrier passed) ----
        if (it + 1 < TOPK) {
            const int kbN = lrow[it + 1];
            const unsigned short* kg = kb16 + ((size_t)h * LLEN + (size_t)kbN * BLK) * DD;
            const unsigned short* vg = vt16 + (size_t)(h * NBLK + kbN) * DD * BLK;
            #pragma unroll
            for (int i = 0; i < 4; ++i) {
                const int is = wid * 4 + i;
                gload16(&Ks[cur ^ 1][is * 512], kg + is * 512 + lane * 8);
                gload16(&Vt[cur ^ 1][is * 512], vg + is * 512 + lane * 8);
            }
        }
        const unsigned short* KsC = &Ks[cur][0];
        const unsigned short* VtC = &Vt[cur][0];

        // ---- S^T = K . Q^T ----
        f32x4 sacc[4];
        #pragma unroll
        for (int mt = 0; mt < 4; ++mt) sacc[mt] = (f32x4){0.f, 0.f, 0.f, 0.f};
        #pragma unroll
        for (int ks = 0; ks < 4; ++ks) {
            #pragma unroll
            for (int mt = 0; mt < 4; ++mt) {
                const int row = mt * 16 + l15;
                const int chunk = (ks * 4 + g) ^ (row & 7);
                bf16x8 kf = *(const bf16x8*)&KsC[row * DD + chunk * 8];
                sacc[mt] = __builtin_amdgcn_mfma_f32_16x16x32_bf16(kf, qhi[ks], sacc[mt], 0, 0, 0);
                sacc[mt] = __builtin_amdgcn_mfma_f32_16x16x32_bf16(kf, qlo[ks], sacc[mt], 0, 0, 0);
            }
        }

        // ---- online softmax ----
        float sv[16];
        #pragma unroll
        for (int mt = 0; mt < 4; ++mt)
            #pragma unroll
            for (int r = 0; r < 4; ++r) sv[mt * 4 + r] = sacc[mt][r];
        float mx = -1e30f;
        #pragma unroll
        for (int i = 0; i < 16; ++i) mx = fmaxf(mx, sv[i]);
        mx = fmaxf(mx, __shfl_xor(mx, 16));
        mx = fmaxf(mx, __shfl_xor(mx, 32));
        const float mnew = fmaxf(m_run, mx);
        const float alpha = __expf(m_run - mnew);
        float ssum = 0.f;
        #pragma unroll
        for (int i = 0; i < 16; ++i) { sv[i] = __expf(sv[i] - mnew); ssum += sv[i]; }
        ssum += __shfl_xor(ssum, 16);
        ssum += __shfl_xor(ssum, 32);
        l_run = l_run * alpha + ssum;
        m_run = mnew;

        // ---- P to LDS (own-wave region; in-wave ordering) ----
        {
            unsigned short* pw = Ps + wid * (16 * BLK) + l15 * BLK;
            #pragma unroll
            for (int mt = 0; mt < 4; ++mt) {
                #pragma unroll
                for (int pr = 0; pr < 2; ++pr) {
                    const int key = mt * 16 + g * 4 + pr * 2;
                    unsigned pak = (unsigned)f2bf(sv[mt * 4 + pr * 2])
                                 | ((unsigned)f2bf(sv[mt * 4 + pr * 2 + 1]) << 16);
                    const int chunk = (key >> 3) ^ (l15 & 7);
                    *(unsigned*)&pw[chunk * 8 + (key & 7)] = pak;
                }
            }
        }

        // ---- O rescale + PV ----
        {
            float ar[4];
            #pragma unroll
            for (int r = 0; r < 4; ++r) ar[r] = __shfl(alpha, g * 4 + r);
            #pragma unroll
            for (int nt = 0; nt < 8; ++nt) {
                Oacc[nt][0] *= ar[0]; Oacc[nt][1] *= ar[1];
                Oacc[nt][2] *= ar[2]; Oacc[nt][3] *= ar[3];
            }
            const unsigned short* prd = Ps + wid * (16 * BLK) + l15 * BLK;
            #pragma unroll
            for (int ks2 = 0; ks2 < 2; ++ks2) {
                const int pch = (g + 4 * ks2) ^ (l15 & 7);
                bf16x8 pa = *(const bf16x8*)&prd[pch * 8];
                #pragma unroll
                for (int nt = 0; nt < 8; ++nt) {
                    const int drow = nt * 16 + l15;
                    const int vch = (g + 4 * ks2) ^ (drow & 7);
                    bf16x8 vf = *(const bf16x8*)&VtC[drow * BLK + vch * 8];
                    Oacc[nt] = __builtin_amdgcn_mfma_f32_16x16x32_bf16(pa, vf, Oacc[nt], 0, 0, 0);
                }
            }
        }
        // lands prefetch (vmcnt0) + protects both buffers + Ps
        __syncthreads();
    }

    // ---- fused linear-attn epilogue: ql softmax + 32 MFMAs vs Mt (L2-hot global) ----
    float qv[32];
    {
        const float iscale = 11.313708498984761f;  // sqrt(D): undo folded scale
        #pragma unroll
        for (int ks = 0; ks < 4; ++ks)
            #pragma unroll
            for (int j = 0; j < 8; ++j)
                qv[ks * 8 + j] = (bf2f((unsigned short)qhi[ks][j])
                                + bf2f((unsigned short)qlo[ks][j])) * iscale;
    }
    float mx2 = -1e30f;
    #pragma unroll
    for (int j = 0; j < 32; ++j) mx2 = fmaxf(mx2, qv[j]);
    mx2 = fmaxf(mx2, __shfl_xor(mx2, 16));
    mx2 = fmaxf(mx2, __shfl_xor(mx2, 32));
    float s2 = 0.f;
    #pragma unroll
    for (int j = 0; j < 32; ++j) { qv[j] = __expf(qv[j] - mx2); s2 += qv[j]; }
    s2 += __shfl_xor(s2, 16);
    s2 += __shfl_xor(s2, 32);
    const float rinv = 1.0f / s2;
    float den = 0.f;
    bf16x8 af[4];
    {
        const float* ksb = ksumf + (size_t)h * DD;
        #pragma unroll
        for (int ks = 0; ks < 4; ++ks) {
            const int dd0 = ks * 32 + g * 8;
            float4 k0 = *(const float4*)(ksb + dd0);
            float4 k1 = *(const float4*)(ksb + dd0 + 4);
            float kk[8] = {k0.x, k0.y, k0.z, k0.w, k1.x, k1.y, k1.z, k1.w};
            #pragma unroll
            for (int j = 0; j < 8; ++j) {
                const float ql = qv[ks * 8 + j] * rinv;
                af[ks][j] = (short)f2bf(ql);
                den += ql * kk[j];
            }
        }
    }
    den += __shfl_xor(den, 16);
    den += __shfl_xor(den, 32);
    const float dinv = 1.0f / (1e-5f + den);

    f32x4 acc2[8];
    #pragma unroll
    for (int nt = 0; nt < 8; ++nt) acc2[nt] = (f32x4){0.f, 0.f, 0.f, 0.f};
    {
        const unsigned short* mrow = Mt + (size_t)h * DD * DD;
        #pragma unroll
        for (int ks = 0; ks < 4; ++ks) {
            #pragma unroll
            for (int nt = 0; nt < 8; ++nt) {
                bf16x8 bf = *(const bf16x8*)&mrow[(size_t)(nt * 16 + l15) * DD + (ks * 4 + g) * 8];
                acc2[nt] = __builtin_amdgcn_mfma_f32_16x16x32_bf16(af[ks], bf, acc2[nt], 0, 0, 0);
            }
        }
    }

    // ---- combine + bias, single store ----
    float bias[8];
    #pragma unroll
    for (int nt = 0; nt < 8; ++nt) bias[nt] = pb[nt * 16 + l15];
    #pragma unroll
    for (int r = 0; r < 4; ++r) {
        const float linv = 1.0f / __shfl(l_run, g * 4 + r);
        const float di = __shfl(dinv, g * 4 + r);
        const int grow = nq * BLK + q0 + g * 4 + r;
        float* dst = out + ((size_t)grow * HH + h) * DD + l15;
        #pragma unroll
        for (int nt = 0; nt < 8; ++nt)
            dst[nt * 16] = Oacc[nt][r] * linv + acc2[nt][r] * di + bias[nt];
    }
}

extern "C" void kernel_launch(void* const* d_in, const int* in_sizes, int n_in,
                              void* d_out, int out_size, void* d_ws, size_t ws_size,
                              hipStream_t stream)
{
    (void)in_sizes; (void)n_in; (void)out_size; (void)ws_size;
    const float* q  = (const float*)d_in[0];
    const float* k  = (const float*)d_in[1];
    const float* v  = (const float*)d_in[2];
    const float* pw = (const float*)d_in[3];
    const float* pb = (const float*)d_in[4];
    float* out = (float*)d_out;
    char* ws = (char*)d_ws;
    size_t off = 0;
    int*   lut   = (int*)(ws + off);   off += (size_t)HH * NBLK * TOPK * 4;
    float* qb    = (float*)(ws + off); off += (size_t)HH * NBLK * DD * 4;
    float* kb    = (float*)(ws + off); off += (size_t)HH * NBLK * DD * 4;
    float* kvp   = (float*)(ws + off); off += (size_t)HH * NCHUNK * DD * DD * 4;
    float* ksp   = (float*)(ws + off); off += (size_t)HH * NCHUNK * 4 * DD * 4;
    unsigned short* Mt = (unsigned short*)(ws + off); off += (size_t)HH * DD * DD * 2;
    float* ksumf = (float*)(ws + off); off += (size_t)HH * DD * 4;
    unsigned short* kb16 = (unsigned short*)(ws + off); off += (size_t)HH * LLEN * DD * 2;
    unsigned short* vt16 = (unsigned short*)(ws + off); off += (size_t)HH * LLEN * DD * 2;

    convert_pool<<<dim3(NBLK, HH), 256, 0, stream>>>(q, k, v, kb16, vt16, qb, kb);
    topk_kernel<<<HH, 256, 0, stream>>>(qb, kb, lut);
    kv_mfma<<<dim3(HH, NCHUNK), 256, 0, stream>>>(k, vt16, kvp, ksp);
    reduce_M<<<dim3(HH, 4), 256, 0, stream>>>(kvp, ksp, pw, Mt, ksumf);
    sla_attn<<<NBLK * HH, 256, 0, stream>>>(q, kb16, vt16, lut, Mt, ksumf, pb, out);
}

// Round 5
// 153.849 us; speedup vs baseline: 4.6187x; 1.0006x over previous
//
#include <hip/hip_runtime.h>
#include <math.h>

#define HH 24
#define LLEN 2048
#define DD 128
#define BLK 64
#define NBLK 32
#define TOPK 16
#define NCHUNK 16

typedef __attribute__((ext_vector_type(8))) short bf16x8;
typedef __attribute__((ext_vector_type(4))) float f32x4;

typedef unsigned int u32_g __attribute__((address_space(1)));
typedef unsigned int u32_l __attribute__((address_space(3)));

__device__ __forceinline__ unsigned short f2bf(float f) {
    unsigned u = __builtin_bit_cast(unsigned, f);
    unsigned r = (u + 0x7FFFu + ((u >> 16) & 1u)) >> 16;
    return (unsigned short)r;
}
__device__ __forceinline__ float bf2f(unsigned short b) {
    unsigned u = ((unsigned)b) << 16;
    return __builtin_bit_cast(float, u);
}
// async 16B/lane global->LDS: lds base is WAVE-UNIFORM (lane0); HW adds lane*16.
__device__ __forceinline__ void gload16(unsigned short* lds, const unsigned short* g) {
    __builtin_amdgcn_global_load_lds((const u32_g*)g, (u32_l*)lds, 16, 0, 0);
}

// ---------------- 1: convert K/V to bf16 (pre-swizzled) + block pooling ----------------
// kb16[h][l][chunk^(l&7)] row-major bf16; vt16[h][ktile][d][keychunk^(d&7)] transposed bf16.
__global__ __launch_bounds__(256) void convert_pool(
    const float* __restrict__ q, const float* __restrict__ k, const float* __restrict__ v,
    unsigned short* __restrict__ kb16, unsigned short* __restrict__ vt16,
    float* __restrict__ qb, float* __restrict__ kb)
{
    const int nb = blockIdx.x, h = blockIdx.y;
    const int l0 = nb * BLK;
    const int tid = threadIdx.x;
    __shared__ unsigned short vt_s[DD * BLK];  // 16 KB

    // ---- K convert: thread = (row r, 32-d slice), swizzled row writes ----
    {
        const int r = tid >> 2, c0 = (tid & 3) * 4;  // c0..c0+3 chunks of 8
        const float* kp = k + ((size_t)(l0 + r) * HH + h) * DD + c0 * 8;
        unsigned short* krow = kb16 + ((size_t)h * LLEN + l0 + r) * DD;
        #pragma unroll
        for (int j = 0; j < 4; ++j) {
            float4 a = *(const float4*)(kp + j * 8);
            float4 c = *(const float4*)(kp + j * 8 + 4);
            unsigned short tmp[8] = {f2bf(a.x), f2bf(a.y), f2bf(a.z), f2bf(a.w),
                                     f2bf(c.x), f2bf(c.y), f2bf(c.z), f2bf(c.w)};
            const int chunk = (c0 + j) ^ (r & 7);
            *(bf16x8*)&krow[chunk * 8] = *(bf16x8*)tmp;
        }
    }
    // ---- V transpose via LDS bounce (packed key-pair u32 writes) ----
    {
        const int kp2 = tid >> 3, dgb = tid & 7;
        const float* v0p = v + ((size_t)(l0 + kp2 * 2) * HH + h) * DD;
        const float* v1p = v0p + (size_t)HH * DD;
        #pragma unroll
        for (int j2 = 0; j2 < 4; ++j2) {
            const int d0 = dgb * 4 + j2 * 32;
            float4 a = *(const float4*)(v0p + d0);
            float4 c = *(const float4*)(v1p + d0);
            float a4[4] = {a.x, a.y, a.z, a.w}, c4[4] = {c.x, c.y, c.z, c.w};
            #pragma unroll
            for (int i = 0; i < 4; ++i) {
                unsigned pak = (unsigned)f2bf(a4[i]) | ((unsigned)f2bf(c4[i]) << 16);
                const int d = d0 + i;
                const int chunk = (kp2 >> 2) ^ (d & 7);
                *(unsigned*)&vt_s[d * BLK + chunk * 8 + (kp2 & 3) * 2] = pak;
            }
        }
    }
    __syncthreads();
    {
        bf16x8* dstv = (bf16x8*)(vt16 + (size_t)(h * NBLK + nb) * DD * BLK);
        const bf16x8* srcv = (const bf16x8*)vt_s;
        #pragma unroll
        for (int j = 0; j < 4; ++j) dstv[tid * 4 + j] = srcv[tid * 4 + j];
    }
    __syncthreads();
    // ---- block-sum pooling for top-k (sums; ranking-invariant scale) ----
    {
        float* ps = (float*)vt_s;
        const int d = tid & 127, half = tid >> 7;
        const size_t rs = (size_t)HH * DD;
        const float* qp = q + ((size_t)(l0 + half * 32) * HH + h) * DD + d;
        const float* kp = k + ((size_t)(l0 + half * 32) * HH + h) * DD + d;
        float sq = 0.f, sk = 0.f;
        #pragma unroll 8
        for (int i = 0; i < 32; ++i) { sq += qp[i * rs]; sk += kp[i * rs]; }
        ps[half * 128 + d] = sq;
        ps[256 + half * 128 + d] = sk;
        __syncthreads();
        if (half == 0) {
            qb[((size_t)h * NBLK + nb) * DD + d] = ps[d] + ps[128 + d];
            kb[((size_t)h * NBLK + nb) * DD + d] = ps[256 + d] + ps[384 + d];
        }
    }
}

// ---------------- 1b: block scores + top-16 LUT ----------------
__global__ __launch_bounds__(256) void topk_kernel(
    const float* __restrict__ qb, const float* __restrict__ kb, int* __restrict__ lut)
{
    const int h = blockIdx.x;
    __shared__ float kb_s[NBLK][DD];
    __shared__ float sc[NBLK][NBLK];
    const int tid = threadIdx.x;
    for (int f = tid; f < NBLK * DD / 4; f += 256)
        ((float4*)kb_s)[f] = ((const float4*)(kb + (size_t)h * NBLK * DD))[f];
    __syncthreads();
    for (int p = tid; p < NBLK * NBLK; p += 256) {
        const int iq = p >> 5, ik = p & 31;
        const float4* qr4 = (const float4*)(qb + ((size_t)h * NBLK + iq) * DD);
        const float4* kr4 = (const float4*)&kb_s[ik][0];
        float s = 0.f;
        for (int dq = 0; dq < DD / 4; ++dq) {
            float4 a = qr4[dq], b = kr4[dq];
            s += a.x * b.x + a.y * b.y + a.z * b.z + a.w * b.w;
        }
        sc[iq][ik] = s;
    }
    __syncthreads();
    if (tid < NBLK) {
        const int iq = tid;
        for (int t = 0; t < TOPK; ++t) {
            float bv = -1e30f; int bi = 0;
            for (int j = 0; j < NBLK; ++j) {
                float s = sc[iq][j];
                if (s > bv) { bv = s; bi = j; }
            }
            lut[((size_t)h * NBLK + iq) * TOPK + t] = bi;
            sc[iq][bi] = -1e30f;
        }
    }
}

// ---------------- 2: kvsum partials via MFMA (128 rows per block) ----------------
__global__ __launch_bounds__(256, 2) void kv_mfma(
    const float* __restrict__ k, const unsigned short* __restrict__ vt16,
    float* __restrict__ kvp, float* __restrict__ ksp)
{
    const int h = blockIdx.x, c = blockIdx.y;
    __shared__ unsigned short klT[DD * DD];  // [d][l] swizzled, 32 KB
    const int tid = threadIdx.x;
    const int quad = tid >> 3, dpart = tid & 7;
    const int d0 = dpart * 16;
    const int wid = tid >> 6, lane = tid & 63;
    const int l15 = lane & 15, g = lane >> 4;

    f32x4 acc[2][8];
    #pragma unroll
    for (int mi = 0; mi < 2; ++mi)
        #pragma unroll
        for (int nt = 0; nt < 8; ++nt) acc[mi][nt] = (f32x4){0.f, 0.f, 0.f, 0.f};
    float ksa[16];
    #pragma unroll
    for (int j = 0; j < 16; ++j) ksa[j] = 0.f;

    const int l0 = c * DD;
    // ---- kl = row-softmax(k), staged transposed ----
    {
        const int lr = quad * 4;
        float rows[4][16];
        #pragma unroll
        for (int i = 0; i < 4; ++i) {
            const float4* kp4 = (const float4*)(k + ((size_t)(l0 + lr + i) * HH + h) * DD + d0);
            #pragma unroll
            for (int t4 = 0; t4 < 4; ++t4) {
                float4 x = kp4[t4];
                rows[i][t4 * 4 + 0] = x.x; rows[i][t4 * 4 + 1] = x.y;
                rows[i][t4 * 4 + 2] = x.z; rows[i][t4 * 4 + 3] = x.w;
            }
        }
        #pragma unroll
        for (int i = 0; i < 4; ++i) {
            float mx = -1e30f;
            #pragma unroll
            for (int j = 0; j < 16; ++j) mx = fmaxf(mx, rows[i][j]);
            mx = fmaxf(mx, __shfl_xor(mx, 1));
            mx = fmaxf(mx, __shfl_xor(mx, 2));
            mx = fmaxf(mx, __shfl_xor(mx, 4));
            float s = 0.f;
            #pragma unroll
            for (int j = 0; j < 16; ++j) { rows[i][j] = __expf(rows[i][j] - mx); s += rows[i][j]; }
            s += __shfl_xor(s, 1);
            s += __shfl_xor(s, 2);
            s += __shfl_xor(s, 4);
            const float rinv = 1.0f / s;
            #pragma unroll
            for (int j = 0; j < 16; ++j) { rows[i][j] *= rinv; ksa[j] += rows[i][j]; }
        }
        #pragma unroll
        for (int j = 0; j < 16; ++j) {
            const int d = d0 + j;
            unsigned long long pk =
                (unsigned long long)f2bf(rows[0][j]) |
                ((unsigned long long)f2bf(rows[1][j]) << 16) |
                ((unsigned long long)f2bf(rows[2][j]) << 32) |
                ((unsigned long long)f2bf(rows[3][j]) << 48);
            const int chunk = (quad >> 1) ^ (d & 7);
            *(unsigned long long*)&klT[d * DD + chunk * 8 + (quad & 1) * 4] = pk;
        }
    }
    __syncthreads();
    // ---- MFMA: A from klT LDS, B direct from global vt16 (L2-hot) ----
    const int bkt = c * 2;
    #pragma unroll
    for (int ks = 0; ks < 4; ++ks) {
        bf16x8 af[2];
        #pragma unroll
        for (int mi = 0; mi < 2; ++mi) {
            const int d = (wid * 2 + mi) * 16 + l15;
            const int chunk = (ks * 4 + g) ^ (d & 7);
            af[mi] = *(const bf16x8*)&klT[d * DD + chunk * 8];
        }
        const int s = ks * 4 + g;
        const int kt = bkt + (s >> 3);
        #pragma unroll
        for (int nt = 0; nt < 8; ++nt) {
            const int e = nt * 16 + l15;
            const int cc = (s & 7) ^ (e & 7);
            bf16x8 bf = *(const bf16x8*)&vt16[((size_t)(h * NBLK + kt) * DD + e) * BLK + cc * 8];
            acc[0][nt] = __builtin_amdgcn_mfma_f32_16x16x32_bf16(af[0], bf, acc[0][nt], 0, 0, 0);
            acc[1][nt] = __builtin_amdgcn_mfma_f32_16x16x32_bf16(af[1], bf, acc[1][nt], 0, 0, 0);
        }
    }
    float* op = kvp + ((size_t)h * NCHUNK + c) * DD * DD;
    #pragma unroll
    for (int mi = 0; mi < 2; ++mi)
        #pragma unroll
        for (int nt = 0; nt < 8; ++nt)
            #pragma unroll
            for (int r = 0; r < 4; ++r)
                op[(size_t)((wid * 2 + mi) * 16 + g * 4 + r) * DD + nt * 16 + l15] = acc[mi][nt][r];
    #pragma unroll
    for (int j = 0; j < 16; ++j) {
        ksa[j] += __shfl_xor(ksa[j], 8);
        ksa[j] += __shfl_xor(ksa[j], 16);
        ksa[j] += __shfl_xor(ksa[j], 32);
    }
    if ((lane >> 3) == 0) {
        float* kp2 = ksp + (((size_t)h * NCHUNK + c) * 4 + wid) * DD + d0;
        #pragma unroll
        for (int j = 0; j < 16; ++j) kp2[j] = ksa[j];
    }
}

// ---------------- 3: reduce partials; Mt = (kvsum @ W^T)^T in bf16; final ksum ----------------
__global__ __launch_bounds__(256) void reduce_M(
    const float* __restrict__ kvp, const float* __restrict__ ksp,
    const float* __restrict__ W, unsigned short* __restrict__ Mt,
    float* __restrict__ ksumf)
{
    const int h = blockIdx.x, rb = blockIdx.y;
    __shared__ float kv_s[32][DD];
    const int tid = threadIdx.x;
    for (int f4 = tid; f4 < 32 * DD / 4; f4 += 256) {
        float4 s = make_float4(0.f, 0.f, 0.f, 0.f);
        #pragma unroll
        for (int cc = 0; cc < NCHUNK; ++cc) {
            float4 x = ((const float4*)(kvp + ((size_t)h * NCHUNK + cc) * DD * DD
                                        + (size_t)rb * 32 * DD))[f4];
            s.x += x.x; s.y += x.y; s.z += x.z; s.w += x.w;
        }
        ((float4*)kv_s)[f4] = s;
    }
    if (rb == 0 && tid < DD) {
        float s = 0.f;
        #pragma unroll
        for (int p = 0; p < NCHUNK * 4; ++p)
            s += ksp[((size_t)h * NCHUNK * 4 + p) * DD + tid];
        ksumf[(size_t)h * DD + tid] = s;
    }
    __syncthreads();
    const int e = tid & 127, dh = tid >> 7;
    float accm[16];
    #pragma unroll
    for (int i = 0; i < 16; ++i) accm[i] = 0.f;
    const float4* wr4 = (const float4*)(W + (size_t)e * DD);
    for (int c4 = 0; c4 < DD / 4; ++c4) {
        const float4 wv = wr4[c4];
        #pragma unroll
        for (int i = 0; i < 16; ++i) {
            const float4 kv4 = ((const float4*)&kv_s[dh * 16 + i][0])[c4];
            accm[i] += kv4.x * wv.x + kv4.y * wv.y + kv4.z * wv.z + kv4.w * wv.w;
        }
    }
    unsigned short* mp = Mt + (size_t)h * DD * DD + (size_t)e * DD + rb * 32 + dh * 16;
    #pragma unroll
    for (int ii = 0; ii < 16; ii += 2) {
        unsigned pk = (unsigned)f2bf(accm[ii]) | ((unsigned)f2bf(accm[ii + 1]) << 16);
        *(unsigned*)&mp[ii] = pk;
    }
}

// ---------------- 4: fused block-sparse flash attention + linear-attn epilogue ----------------
// Double-buffered async global->LDS staging from pre-swizzled bf16 buffers; 1 barrier/iter.
__global__ __launch_bounds__(256, 2) void sla_attn(
    const float* __restrict__ q, const unsigned short* __restrict__ kb16,
    const unsigned short* __restrict__ vt16, const int* __restrict__ lut,
    const unsigned short* __restrict__ Mt, const float* __restrict__ ksumf,
    const float* __restrict__ pb, float* __restrict__ out)
{
    const int b = blockIdx.x;
    const int slot = b >> 3;
    const int h = (b & 7) + 8 * (slot >> 5);
    const int nq = slot & 31;

    __shared__ unsigned short Ks[2][BLK * DD];   // 2 x 16 KB
    __shared__ unsigned short Vt[2][DD * BLK];   // 2 x 16 KB
    __shared__ unsigned short Ps[4 * 16 * BLK];  // 8 KB

    const int tid = threadIdx.x;
    const int wid = tid >> 6, lane = tid & 63;
    const int l15 = lane & 15, g = lane >> 4;
    const int q0 = wid * 16;

    // ---- Q fragments: scale folded, hi/lo split, stationary ----
    bf16x8 qhi[4], qlo[4];
    {
        const float scale = 0.08838834764831845f;
        const int qrow = nq * BLK + q0 + l15;
        const float* qp = q + ((size_t)qrow * HH + h) * DD;
        #pragma unroll
        for (int ks = 0; ks < 4; ++ks) {
            const int d0 = ks * 32 + g * 8;
            float4 a = *(const float4*)(qp + d0);
            float4 c = *(const float4*)(qp + d0 + 4);
            float vv[8] = {a.x, a.y, a.z, a.w, c.x, c.y, c.z, c.w};
            #pragma unroll
            for (int j = 0; j < 8; ++j) {
                float s = vv[j] * scale;
                unsigned short hi = f2bf(s);
                float lo = s - bf2f(hi);
                qhi[ks][j] = (short)hi;
                qlo[ks][j] = (short)f2bf(lo);
            }
        }
    }

    f32x4 Oacc[8];
    #pragma unroll
    for (int nt = 0; nt < 8; ++nt) Oacc[nt] = (f32x4){0.f, 0.f, 0.f, 0.f};
    float m_run = -1e30f, l_run = 0.f;

    const int* lrow = lut + ((size_t)h * NBLK + nq) * TOPK;

    // prologue: stage tile 0 into buf 0 (wave w does issues 4w..4w+3 of K and V)
    {
        const int kbI = lrow[0];
        const unsigned short* kg = kb16 + ((size_t)h * LLEN + (size_t)kbI * BLK) * DD;
        const unsigned short* vg = vt16 + (size_t)(h * NBLK + kbI) * DD * BLK;
        #pragma unroll
        for (int i = 0; i < 4; ++i) {
            const int is = wid * 4 + i;
            gload16(&Ks[0][is * 512], kg + is * 512 + lane * 8);
            gload16(&Vt[0][is * 512], vg + is * 512 + lane * 8);
        }
    }
    __syncthreads();

    for (int it = 0; it < TOPK; ++it) {
        const int cur = it & 1;
        // ---- prefetch next tile into the other buffer (consumed at it-1; barrier passed) ----
        if (it + 1 < TOPK) {
            const int kbN = lrow[it + 1];
            const unsigned short* kg = kb16 + ((size_t)h * LLEN + (size_t)kbN * BLK) * DD;
            const unsigned short* vg = vt16 + (size_t)(h * NBLK + kbN) * DD * BLK;
            #pragma unroll
            for (int i = 0; i < 4; ++i) {
                const int is = wid * 4 + i;
                gload16(&Ks[cur ^ 1][is * 512], kg + is * 512 + lane * 8);
                gload16(&Vt[cur ^ 1][is * 512], vg + is * 512 + lane * 8);
            }
        }
        const unsigned short* KsC = &Ks[cur][0];
        const unsigned short* VtC = &Vt[cur][0];

        // ---- S^T = K . Q^T ----
        f32x4 sacc[4];
        #pragma unroll
        for (int mt = 0; mt < 4; ++mt) sacc[mt] = (f32x4){0.f, 0.f, 0.f, 0.f};
        #pragma unroll
        for (int ks = 0; ks < 4; ++ks) {
            #pragma unroll
            for (int mt = 0; mt < 4; ++mt) {
                const int row = mt * 16 + l15;
                const int chunk = (ks * 4 + g) ^ (row & 7);
                bf16x8 kf = *(const bf16x8*)&KsC[row * DD + chunk * 8];
                sacc[mt] = __builtin_amdgcn_mfma_f32_16x16x32_bf16(kf, qhi[ks], sacc[mt], 0, 0, 0);
                sacc[mt] = __builtin_amdgcn_mfma_f32_16x16x32_bf16(kf, qlo[ks], sacc[mt], 0, 0, 0);
            }
        }

        // ---- online softmax ----
        float sv[16];
        #pragma unroll
        for (int mt = 0; mt < 4; ++mt)
            #pragma unroll
            for (int r = 0; r < 4; ++r) sv[mt * 4 + r] = sacc[mt][r];
        float mx = -1e30f;
        #pragma unroll
        for (int i = 0; i < 16; ++i) mx = fmaxf(mx, sv[i]);
        mx = fmaxf(mx, __shfl_xor(mx, 16));
        mx = fmaxf(mx, __shfl_xor(mx, 32));
        const float mnew = fmaxf(m_run, mx);
        const float alpha = __expf(m_run - mnew);
        float ssum = 0.f;
        #pragma unroll
        for (int i = 0; i < 16; ++i) { sv[i] = __expf(sv[i] - mnew); ssum += sv[i]; }
        ssum += __shfl_xor(ssum, 16);
        ssum += __shfl_xor(ssum, 32);
        l_run = l_run * alpha + ssum;
        m_run = mnew;

        // ---- P to LDS (own-wave region; in-wave ordering) ----
        {
            unsigned short* pw = Ps + wid * (16 * BLK) + l15 * BLK;
            #pragma unroll
            for (int mt = 0; mt < 4; ++mt) {
                #pragma unroll
                for (int pr = 0; pr < 2; ++pr) {
                    const int key = mt * 16 + g * 4 + pr * 2;
                    unsigned pak = (unsigned)f2bf(sv[mt * 4 + pr * 2])
                                 | ((unsigned)f2bf(sv[mt * 4 + pr * 2 + 1]) << 16);
                    const int chunk = (key >> 3) ^ (l15 & 7);
                    *(unsigned*)&pw[chunk * 8 + (key & 7)] = pak;
                }
            }
        }

        // ---- O rescale + PV ----
        {
            float ar[4];
            #pragma unroll
            for (int r = 0; r < 4; ++r) ar[r] = __shfl(alpha, g * 4 + r);
            #pragma unroll
            for (int nt = 0; nt < 8; ++nt) {
                Oacc[nt][0] *= ar[0]; Oacc[nt][1] *= ar[1];
                Oacc[nt][2] *= ar[2]; Oacc[nt][3] *= ar[3];
            }
            const unsigned short* prd = Ps + wid * (16 * BLK) + l15 * BLK;
            #pragma unroll
            for (int ks2 = 0; ks2 < 2; ++ks2) {
                const int pch = (g + 4 * ks2) ^ (l15 & 7);
                bf16x8 pa = *(const bf16x8*)&prd[pch * 8];
                #pragma unroll
                for (int nt = 0; nt < 8; ++nt) {
                    const int drow = nt * 16 + l15;
                    const int vch = (g + 4 * ks2) ^ (drow & 7);
                    bf16x8 vf = *(const bf16x8*)&VtC[drow * BLK + vch * 8];
                    Oacc[nt] = __builtin_amdgcn_mfma_f32_16x16x32_bf16(pa, vf, Oacc[nt], 0, 0, 0);
                }
            }
        }
        // lands prefetch (vmcnt0) + protects both buffers + Ps
        __syncthreads();
    }

    // ---- fused linear-attn epilogue: ql softmax + 32 MFMAs vs Mt (L2-hot global) ----
    float qv[32];
    {
        const float iscale = 11.313708498984761f;  // sqrt(D): undo folded scale
        #pragma unroll
        for (int ks = 0; ks < 4; ++ks)
            #pragma unroll
            for (int j = 0; j < 8; ++j)
                qv[ks * 8 + j] = (bf2f((unsigned short)qhi[ks][j])
                                + bf2f((unsigned short)qlo[ks][j])) * iscale;
    }
    float mx2 = -1e30f;
    #pragma unroll
    for (int j = 0; j < 32; ++j) mx2 = fmaxf(mx2, qv[j]);
    mx2 = fmaxf(mx2, __shfl_xor(mx2, 16));
    mx2 = fmaxf(mx2, __shfl_xor(mx2, 32));
    float s2 = 0.f;
    #pragma unroll
    for (int j = 0; j < 32; ++j) { qv[j] = __expf(qv[j] - mx2); s2 += qv[j]; }
    s2 += __shfl_xor(s2, 16);
    s2 += __shfl_xor(s2, 32);
    const float rinv = 1.0f / s2;
    float den = 0.f;
    bf16x8 af[4];
    {
        const float* ksb = ksumf + (size_t)h * DD;
        #pragma unroll
        for (int ks = 0; ks < 4; ++ks) {
            const int dd0 = ks * 32 + g * 8;
            float4 k0 = *(const float4*)(ksb + dd0);
            float4 k1 = *(const float4*)(ksb + dd0 + 4);
            float kk[8] = {k0.x, k0.y, k0.z, k0.w, k1.x, k1.y, k1.z, k1.w};
            #pragma unroll
            for (int j = 0; j < 8; ++j) {
                const float ql = qv[ks * 8 + j] * rinv;
                af[ks][j] = (short)f2bf(ql);
                den += ql * kk[j];
            }
        }
    }
    den += __shfl_xor(den, 16);
    den += __shfl_xor(den, 32);
    const float dinv = 1.0f / (1e-5f + den);

    f32x4 acc2[8];
    #pragma unroll
    for (int nt = 0; nt < 8; ++nt) acc2[nt] = (f32x4){0.f, 0.f, 0.f, 0.f};
    {
        const unsigned short* mrow = Mt + (size_t)h * DD * DD;
        #pragma unroll
        for (int ks = 0; ks < 4; ++ks) {
            #pragma unroll
            for (int nt = 0; nt < 8; ++nt) {
                bf16x8 bf = *(const bf16x8*)&mrow[(size_t)(nt * 16 + l15) * DD + (ks * 4 + g) * 8];
                acc2[nt] = __builtin_amdgcn_mfma_f32_16x16x32_bf16(af[ks], bf, acc2[nt], 0, 0, 0);
            }
        }
    }

    // ---- combine + bias, single store ----
    float bias[8];
    #pragma unroll
    for (int nt = 0; nt < 8; ++nt) bias[nt] = pb[nt * 16 + l15];
    #pragma unroll
    for (int r = 0; r < 4; ++r) {
        const float linv = 1.0f / __shfl(l_run, g * 4 + r);
        const float di = __shfl(dinv, g * 4 + r);
        const int grow = nq * BLK + q0 + g * 4 + r;
        float* dst = out + ((size_t)grow * HH + h) * DD + l15;
        #pragma unroll
        for (int nt = 0; nt < 8; ++nt)
            dst[nt * 16] = Oacc[nt][r] * linv + acc2[nt][r] * di + bias[nt];
    }
}

extern "C" void kernel_launch(void* const* d_in, const int* in_sizes, int n_in,
                              void* d_out, int out_size, void* d_ws, size_t ws_size,
                              hipStream_t stream)
{
    (void)in_sizes; (void)n_in; (void)out_size; (void)ws_size;
    const float* q  = (const float*)d_in[0];
    const float* k  = (const float*)d_in[1];
    const float* v  = (const float*)d_in[2];
    const float* pw = (const float*)d_in[3];
    const float* pb = (const float*)d_in[4];
    float* out = (float*)d_out;
    char* ws = (char*)d_ws;
    size_t off = 0;
    int*   lut   = (int*)(ws + off);   off += (size_t)HH * NBLK * TOPK * 4;
    float* qb    = (float*)(ws + off); off += (size_t)HH * NBLK * DD * 4;
    float* kb    = (float*)(ws + off); off += (size_t)HH * NBLK * DD * 4;
    float* kvp   = (float*)(ws + off); off += (size_t)HH * NCHUNK * DD * DD * 4;
    float* ksp   = (float*)(ws + off); off += (size_t)HH * NCHUNK * 4 * DD * 4;
    unsigned short* Mt = (unsigned short*)(ws + off); off += (size_t)HH * DD * DD * 2;
    float* ksumf = (float*)(ws + off); off += (size_t)HH * DD * 4;
    unsigned short* kb16 = (unsigned short*)(ws + off); off += (size_t)HH * LLEN * DD * 2;
    unsigned short* vt16 = (unsigned short*)(ws + off); off += (size_t)HH * LLEN * DD * 2;

    convert_pool<<<dim3(NBLK, HH), 256, 0, stream>>>(q, k, v, kb16, vt16, qb, kb);
    topk_kernel<<<HH, 256, 0, stream>>>(qb, kb, lut);
    kv_mfma<<<dim3(HH, NCHUNK), 256, 0, stream>>>(k, vt16, kvp, ksp);
    reduce_M<<<dim3(HH, 4), 256, 0, stream>>>(kvp, ksp, pw, Mt, ksumf);
    sla_attn<<<NBLK * HH, 256, 0, stream>>>(q, kb16, vt16, lut, Mt, ksumf, pb, out);
}